// Round 5
// baseline (5262.162 us; speedup 1.0000x reference)
//
#include <hip/hip_runtime.h>
#include <math.h>

// Problem dims
#define NBATCH 32
#define NPOS   1024
#define NTOK   32768          // NBATCH*NPOS
#define DMODEL 512
#define NHEAD  8
#define DHD    64
#define NROWS  262144         // NTOK*NHEAD
#define MMR    266            // random-feature count
#define NDFF   2048
#define NEXP   4
#define CIN    128            // PL*CIN = flattened patch dim

#define DNSC   0.35355339059327373f   // 64^-0.25
#define RSM    0.06131393394849658f   // 266^-0.5
#define NEG_INF -3.0e38f

typedef _Float16 half8 __attribute__((ext_vector_type(8)));
typedef _Float16 half4 __attribute__((ext_vector_type(4)));
typedef float    f32x4 __attribute__((ext_vector_type(4)));

// ---------------- workspace layout (float offsets) ----------------
static const size_t F_BUF1 = 0;          // 16777216 (K -> Q -> pre -> Z)
static const size_t F_CTX  = 16777216;   // 4358144 (256*266*64); reused for fp16 weights after attn
static const size_t F_KSUM = 21135360;   // 68096 (256*266)
static const size_t F_PART = 21203456;   // 2048
static const size_t F_STAB = 21205504;   // 16
static const size_t F_EFF  = 21205520;   // 3*512*128 = 196608
static const size_t F_CNTI = 21402128;   // 16 (ints)
static const size_t F_TOKI = 21402144;   // 4*32768 ints
static const size_t F_GWF  = 21533216;   // 4*32768 floats
static const size_t F_PJT  = 21664288;   // 20480 floats: packed proj [64][16][20]
static const size_t F_END  = 21684768;

// 17-term register accumulate from the packed proj fragment
#define DASH17(da, q) \
  da[0]+=q*pA.x; da[1]+=q*pA.y; da[2]+=q*pA.z; da[3]+=q*pA.w; \
  da[4]+=q*pB.x; da[5]+=q*pB.y; da[6]+=q*pB.z; da[7]+=q*pB.w; \
  da[8]+=q*pC.x; da[9]+=q*pC.y; da[10]+=q*pC.z; da[11]+=q*pC.w; \
  da[12]+=q*pD.x; da[13]+=q*pD.y; da[14]+=q*pD.z; da[15]+=q*pD.w; \
  da[16]+=q*pE;

// ---------------- fallback (ws too small): write zeros, fail cleanly -----------
__global__ __launch_bounds__(256) void fallback_zero_kernel(float* __restrict__ out) {
  out[(size_t)blockIdx.x * 256 + threadIdx.x] = 0.f;
}

// ---------------- pack proj: projT[d*320 + g*20 + j] = proj[(g*17+j)*64 + d] ----------
__global__ __launch_bounds__(256) void proj_pack_kernel(
    const float* __restrict__ proj, float* __restrict__ projT)
{
  int idx = blockIdx.x * 256 + threadIdx.x;
  if (idx >= 20480) return;
  int d = idx / 320, rem = idx % 320;
  int g = rem / 20, j = rem % 20;
  int m = g * 17 + j;
  projT[idx] = (j < 17 && m < MMR) ? proj[m * 64 + d] : 0.f;
}

// ---------------- effective QKV matrices: eff[mat] = W[mat] @ emb_w  (512x128) ----------
__global__ __launch_bounds__(128) void effmat_kernel(
    const float* __restrict__ wq, const float* __restrict__ wk, const float* __restrict__ wv,
    const float* __restrict__ emb, float* __restrict__ eff)
{
  __shared__ float wrow[512];
  const int bid = blockIdx.x;          // 0..1535
  const int mat = bid >> 9;
  const int n   = bid & 511;
  const float* W = (mat == 0) ? wq : ((mat == 1) ? wk : wv);
  const int tid = threadIdx.x;         // 128
  for (int i = tid; i < 512; i += 128) wrow[i] = W[n * 512 + i];
  __syncthreads();
  float acc = 0.f;
  for (int d = 0; d < 512; ++d) acc += wrow[d] * emb[d * CIN + tid];
  eff[mat * 65536 + n * CIN + tid] = acc;
}

// ------- generic GEMM: C = A(MxK)*W(NxK)^T [+ A2(MxK2)*W2(NxK2)^T] + bias --------------
__global__ __launch_bounds__(256) void gemm_nt_kernel(
    const float* __restrict__ A, const float* __restrict__ W, int K,
    const float* __restrict__ A2, const float* __restrict__ W2, int K2,
    const float* __restrict__ bias, float* __restrict__ C, int N, int ncb)
{
  __shared__ float As[32][64];
  __shared__ float Ws[32][64];
  const int tid  = threadIdx.x;
  const int bx   = blockIdx.x % ncb;
  const int by   = blockIdx.x / ncb;
  const int row0 = by * 64, col0 = bx * 64;
  const int tx   = tid & 15, ty = tid >> 4;
  const int lr   = tid >> 3;
  const int lk   = (tid & 7) * 4;
  float acc[4][4] = {};
  for (int pass = 0; pass < 2; ++pass) {
    const float* Ap = pass ? A2 : A;
    const float* Wp = pass ? W2 : W;
    const int    Kp = pass ? K2 : K;
    if (!Ap) continue;
    for (int k0 = 0; k0 < Kp; k0 += 32) {
      __syncthreads();
#pragma unroll
      for (int rr = 0; rr < 2; ++rr) {
        const int r = lr + rr * 32;
        float4 a4 = *(const float4*)&Ap[(size_t)(row0 + r) * Kp + k0 + lk];
        As[lk + 0][r] = a4.x; As[lk + 1][r] = a4.y; As[lk + 2][r] = a4.z; As[lk + 3][r] = a4.w;
        float4 w4 = *(const float4*)&Wp[(size_t)(col0 + r) * Kp + k0 + lk];
        Ws[lk + 0][r] = w4.x; Ws[lk + 1][r] = w4.y; Ws[lk + 2][r] = w4.z; Ws[lk + 3][r] = w4.w;
      }
      __syncthreads();
#pragma unroll
      for (int kk = 0; kk < 32; ++kk) {
        float4 av = *(const float4*)&As[kk][ty * 4];
        float4 wv = *(const float4*)&Ws[kk][tx * 4];
        acc[0][0] += av.x * wv.x; acc[0][1] += av.x * wv.y; acc[0][2] += av.x * wv.z; acc[0][3] += av.x * wv.w;
        acc[1][0] += av.y * wv.x; acc[1][1] += av.y * wv.y; acc[1][2] += av.y * wv.z; acc[1][3] += av.y * wv.w;
        acc[2][0] += av.z * wv.x; acc[2][1] += av.z * wv.y; acc[2][2] += av.z * wv.z; acc[2][3] += av.z * wv.w;
        acc[3][0] += av.w * wv.x; acc[3][1] += av.w * wv.y; acc[3][2] += av.w * wv.z; acc[3][3] += av.w * wv.w;
      }
    }
  }
#pragma unroll
  for (int i = 0; i < 4; ++i) {
    const int row = row0 + ty * 4 + i;
    const int col = col0 + tx * 4;
    float4 o = make_float4(acc[i][0], acc[i][1], acc[i][2], acc[i][3]);
    if (bias) {
      float4 b4 = *(const float4*)&bias[col];
      o.x += b4.x; o.y += b4.y; o.z += b4.z; o.w += b4.w;
    }
    *(float4*)&C[(size_t)row * N + col] = o;
  }
}

// ---------------- global max of k-dash: 1024 thr, 512 rows/block ----------------
__global__ __launch_bounds__(1024) void kdash_max_kernel(
    const float* __restrict__ Kbuf, const float* __restrict__ projT, float* __restrict__ partial)
{
  __shared__ float pjG[20480];
  __shared__ float kl[32 * 68];
  __shared__ float red[1024];
  const int tid = threadIdx.x;
  for (int i = tid; i < 20480; i += 1024) pjG[i] = projT[i];
  const int w = tid >> 6, l = tid & 63;
  const int ml = l & 15, ds = l >> 4;
  const int dbase = ds * 16;
  const int r0 = 2 * w;
  float mxl = NEG_INF;
  for (int t = 0; t < 16; ++t) {
    __syncthreads();
    for (int idx = tid; idx < 2048; idx += 1024) {
      int r = idx >> 6, dd = idx & 63;
      kl[r * 68 + dd] = Kbuf[((size_t)blockIdx.x * 512 + t * 32 + r) * 64 + dd] * DNSC;
    }
    __syncthreads();
    float da0[17], da1[17];
#pragma unroll
    for (int j = 0; j < 17; ++j) { da0[j] = 0.f; da1[j] = 0.f; }
    for (int dd = 0; dd < 16; ++dd) {
      int d = dbase + dd;
      float q0 = kl[r0 * 68 + d], q1 = kl[r0 * 68 + 68 + d];
      const float* pr = &pjG[d * 320 + ml * 20];
      float4 pA = *(const float4*)pr, pB = *(const float4*)(pr + 4),
             pC = *(const float4*)(pr + 8), pD = *(const float4*)(pr + 12);
      float pE = pr[16];
      DASH17(da0, q0)
      DASH17(da1, q1)
    }
#pragma unroll
    for (int j = 0; j < 17; ++j) {
      da0[j] += __shfl_xor(da0[j], 16); da0[j] += __shfl_xor(da0[j], 32);
      da1[j] += __shfl_xor(da1[j], 16); da1[j] += __shfl_xor(da1[j], 32);
    }
#pragma unroll
    for (int j = 0; j < 17; ++j) {
      int m = ml * 17 + j;
      if (m < MMR) { mxl = fmaxf(mxl, da0[j]); mxl = fmaxf(mxl, da1[j]); }
    }
  }
  red[tid] = mxl;
  __syncthreads();
  for (int st = 512; st > 0; st >>= 1) {
    if (tid < st) red[tid] = fmaxf(red[tid], red[tid + st]);
    __syncthreads();
  }
  if (tid == 0) partial[blockIdx.x] = red[0];
}

__global__ __launch_bounds__(256) void reduce_max_kernel(
    const float* __restrict__ part, float* __restrict__ stab, int n)
{
  __shared__ float red[256];
  float m = NEG_INF;
  for (int i = threadIdx.x; i < n; i += 256) m = fmaxf(m, part[i]);
  red[threadIdx.x] = m;
  __syncthreads();
  for (int st = 128; st > 0; st >>= 1) {
    if (threadIdx.x < st) red[threadIdx.x] = fmaxf(red[threadIdx.x], red[threadIdx.x + st]);
    __syncthreads();
  }
  if (threadIdx.x == 0) stab[0] = red[0];
}

// ---------------- ctx = kp^T @ v, ksum = sum kp; one (b,h) per block, 1024 thr ----------
__global__ __launch_bounds__(1024) void ctx_kernel(
    const float* __restrict__ Kbuf, const float* __restrict__ Vbuf,
    const float* __restrict__ projT, const float* __restrict__ stabp,
    float* __restrict__ ctxg, float* __restrict__ ksumg)
{
  __shared__ float pjG[20480];
  __shared__ float kl[32 * 68];
  __shared__ float vl[32 * 68];
  __shared__ _Float16 kp16[32 * 320];
  __shared__ float ks[272];
  const int tid = threadIdx.x;
  const int bh = blockIdx.x;
  const int b = bh >> 3, h = bh & 7;
  const float stab = stabp[0];
  for (int i = tid; i < 20480; i += 1024) pjG[i] = projT[i];
  if (tid < 272) ks[tid] = 0.f;
  const int w = tid >> 6, l = tid & 63;
  const int ml = l & 15, ds = l >> 4;
  const int dbase = ds * 16;
  const int r0 = 2 * w;
  const int jh = ds >> 1, rsel = ds & 1;
  const int d = tid & 63, mg = tid >> 6;
  // ks-pass ids (tid < 544)
  const int ksm = tid >> 1, ksih = tid & 1;
  const int ksg = ksm / 17, ksj = ksm - ksg * 17;
  float acc[17];
#pragma unroll
  for (int j = 0; j < 17; ++j) acc[j] = 0.f;

  for (int t = 0; t < 32; ++t) {
    __syncthreads();
    for (int idx = tid; idx < 2048; idx += 1024) {
      int r = idx >> 6, dd = idx & 63;
      size_t g = ((size_t)(b * NPOS + t * 32 + r)) * DMODEL + h * DHD + dd;
      kl[r * 68 + dd] = Kbuf[g] * DNSC;
      vl[r * 68 + dd] = Vbuf[g];
    }
    __syncthreads();
    // dash for rows r0, r0+1 (partial over d-quarter, reduce over ds)
    float da0[17], da1[17]; float dg0 = 0.f, dg1 = 0.f;
#pragma unroll
    for (int j = 0; j < 17; ++j) { da0[j] = 0.f; da1[j] = 0.f; }
    for (int dd = 0; dd < 16; ++dd) {
      int dq = dbase + dd;
      float q0 = kl[r0 * 68 + dq], q1 = kl[r0 * 68 + 68 + dq];
      const float* pr = &pjG[dq * 320 + ml * 20];
      float4 pA = *(const float4*)pr, pB = *(const float4*)(pr + 4),
             pC = *(const float4*)(pr + 8), pD = *(const float4*)(pr + 12);
      float pE = pr[16];
      dg0 += q0 * q0; dg1 += q1 * q1;
      DASH17(da0, q0)
      DASH17(da1, q1)
    }
#pragma unroll
    for (int j = 0; j < 17; ++j) {
      da0[j] += __shfl_xor(da0[j], 16); da0[j] += __shfl_xor(da0[j], 32);
      da1[j] += __shfl_xor(da1[j], 16); da1[j] += __shfl_xor(da1[j], 32);
    }
    dg0 += __shfl_xor(dg0, 16); dg0 += __shfl_xor(dg0, 32);
    dg1 += __shfl_xor(dg1, 16); dg1 += __shfl_xor(dg1, 32);
    // exp: lane handles row r0+rsel, strided j = 2k+jh
    float dgx = rsel ? dg1 : dg0;
    const int irow = r0 + rsel;
#pragma unroll
    for (int k = 0; k < 9; ++k) {
      int j = 2 * k + jh;
      if (j < 17) {
        int m = ml * 17 + j;
        float dv = rsel ? da1[j] : da0[j];
        float v = 0.f;
        if (m < MMR) v = RSM * (expf(dv - 0.5f * dgx - stab) + 1e-4f);
        kp16[irow * 320 + ml * 20 + j] = (_Float16)v;
      }
    }
    __syncthreads();
    // ksum accumulation
    if (tid < 544) {
      float s = 0.f;
      const _Float16* kb = &kp16[ksih * 16 * 320 + ksg * 20 + ksj];
#pragma unroll
      for (int i = 0; i < 16; ++i) s += (float)kb[i * 320];
      s += __shfl_xor(s, 1);
      if (ksih == 0) ks[ksm] += s;
    }
    // PV: acc[j] += kp[i][mg*17+j] * v[i][d]
    for (int i = 0; i < 32; ++i) {
      float vv = vl[i * 68 + d];
      const _Float16* kr = &kp16[i * 320 + mg * 20];
      half4 k0 = *(const half4*)kr;
      half4 k1 = *(const half4*)(kr + 4);
      half4 k2 = *(const half4*)(kr + 8);
      half4 k3 = *(const half4*)(kr + 12);
      float kE = (float)kr[16];
      acc[0] += (float)k0.x * vv; acc[1] += (float)k0.y * vv; acc[2] += (float)k0.z * vv; acc[3] += (float)k0.w * vv;
      acc[4] += (float)k1.x * vv; acc[5] += (float)k1.y * vv; acc[6] += (float)k1.z * vv; acc[7] += (float)k1.w * vv;
      acc[8] += (float)k2.x * vv; acc[9] += (float)k2.y * vv; acc[10] += (float)k2.z * vv; acc[11] += (float)k2.w * vv;
      acc[12] += (float)k3.x * vv; acc[13] += (float)k3.y * vv; acc[14] += (float)k3.z * vv; acc[15] += (float)k3.w * vv;
      acc[16] += kE * vv;
    }
  }
  __syncthreads();
  const size_t cb = (size_t)bh * MMR * DHD;
#pragma unroll
  for (int j = 0; j < 17; ++j) {
    int m = mg * 17 + j;
    if (m < MMR) ctxg[cb + (size_t)m * 64 + d] = acc[j];
  }
  if (tid < MMR) ksumg[bh * MMR + tid] = ks[tid];
}

// ---------------- attn = (qp @ ctx)/den; 1024 thr, 64 rows/block ----------------
__global__ __launch_bounds__(1024) void attn_kernel(
    const float* __restrict__ Qbuf, const float* __restrict__ ctxg,
    const float* __restrict__ ksumg, const float* __restrict__ projT,
    float* __restrict__ attnb)
{
  __shared__ float pjG[20480];
  __shared__ float ql[64 * 68];
  __shared__ _Float16 qp16[64 * 272];
  __shared__ float ks[272];
  __shared__ float den_s[64];
  const int tid = threadIdx.x;
  const int bh = blockIdx.x >> 4;
  const int n0 = (blockIdx.x & 15) * 64;
  const int b = bh >> 3, h = bh & 7;
  for (int i = tid; i < 20480; i += 1024) pjG[i] = projT[i];
  if (tid < 272) ks[tid] = (tid < MMR) ? ksumg[bh * MMR + tid] : 0.f;
  for (int idx = tid; idx < 4096; idx += 1024) {
    int r = idx >> 6, dd = idx & 63;
    ql[r * 68 + dd] = Qbuf[((size_t)(b * NPOS + n0 + r)) * DMODEL + h * DHD + dd] * DNSC;
  }
  __syncthreads();
  const int w = tid >> 6, l = tid & 63;
  const int ml = l & 15, ds = l >> 4;
  const int dbase = ds * 16;
  const int jh = ds >> 1, rsel = ds & 1;
  for (int s = 0; s < 2; ++s) {
    const int r0 = s * 32 + 2 * w;
    float da0[17], da1[17]; float dg0 = 0.f, dg1 = 0.f;
#pragma unroll
    for (int j = 0; j < 17; ++j) { da0[j] = 0.f; da1[j] = 0.f; }
    for (int dd = 0; dd < 16; ++dd) {
      int dq = dbase + dd;
      float q0 = ql[r0 * 68 + dq], q1 = ql[r0 * 68 + 68 + dq];
      const float* pr = &pjG[dq * 320 + ml * 20];
      float4 pA = *(const float4*)pr, pB = *(const float4*)(pr + 4),
             pC = *(const float4*)(pr + 8), pD = *(const float4*)(pr + 12);
      float pE = pr[16];
      dg0 += q0 * q0; dg1 += q1 * q1;
      DASH17(da0, q0)
      DASH17(da1, q1)
    }
#pragma unroll
    for (int j = 0; j < 17; ++j) {
      da0[j] += __shfl_xor(da0[j], 16); da0[j] += __shfl_xor(da0[j], 32);
      da1[j] += __shfl_xor(da1[j], 16); da1[j] += __shfl_xor(da1[j], 32);
    }
    dg0 += __shfl_xor(dg0, 16); dg0 += __shfl_xor(dg0, 32);
    dg1 += __shfl_xor(dg1, 16); dg1 += __shfl_xor(dg1, 32);
    // per-row max over valid m (reduce over ml-groups)
    float mx0 = NEG_INF, mx1 = NEG_INF;
#pragma unroll
    for (int j = 0; j < 17; ++j) {
      int m = ml * 17 + j;
      if (m < MMR) { mx0 = fmaxf(mx0, da0[j]); mx1 = fmaxf(mx1, da1[j]); }
    }
#pragma unroll
    for (int off = 1; off < 16; off <<= 1) {
      mx0 = fmaxf(mx0, __shfl_xor(mx0, off));
      mx1 = fmaxf(mx1, __shfl_xor(mx1, off));
    }
    float dgx = rsel ? dg1 : dg0;
    float mxx = rsel ? mx1 : mx0;
    const int row = r0 + rsel;
    float dp = 0.f;
#pragma unroll
    for (int k = 0; k < 9; ++k) {
      int j = 2 * k + jh;
      if (j < 17) {
        int m = ml * 17 + j;
        float dv = rsel ? da1[j] : da0[j];
        float v = 0.f;
        if (m < MMR) { v = RSM * (expf(dv - 0.5f * dgx - mxx) + 1e-4f); dp += v * ks[m]; }
        qp16[row * 272 + m] = (_Float16)v;
      }
    }
    dp += __shfl_xor(dp, 1); dp += __shfl_xor(dp, 2); dp += __shfl_xor(dp, 4);
    dp += __shfl_xor(dp, 8); dp += __shfl_xor(dp, 32);
    if ((l & 47) == 0) den_s[row] = dp;
  }
  __syncthreads();
  // PV: wave wg owns 4 rows, lane = output d
  const int wg = tid >> 6, lane = tid & 63;
  float acc[4] = {0.f, 0.f, 0.f, 0.f};
  const float* cb = ctxg + (size_t)bh * MMR * DHD + lane;
  for (int m0 = 0; m0 < 272; m0 += 4) {
    float c0 = cb[(size_t)(m0 + 0) * 64];
    float c1 = cb[(size_t)(m0 + 1) * 64];
    float c2 = cb[(size_t)(m0 + 2) * 64];
    float c3 = cb[(size_t)(m0 + 3) * 64];
#pragma unroll
    for (int tt = 0; tt < 4; ++tt) {
      half4 q4 = *(const half4*)&qp16[(wg * 4 + tt) * 272 + m0];
      acc[tt] += (float)q4.x * c0 + (float)q4.y * c1 + (float)q4.z * c2 + (float)q4.w * c3;
    }
  }
#pragma unroll
  for (int tt = 0; tt < 4; ++tt) {
    int r = wg * 4 + tt;
    attnb[((size_t)(b * NPOS + n0 + r)) * DMODEL + h * DHD + lane] = acc[tt] / den_s[r];
  }
}

// ---------------- LayerNorm (one block per row); optional second output ----------------
__global__ __launch_bounds__(256) void ln_kernel(
    const float* __restrict__ in, const float* __restrict__ g, const float* __restrict__ bb,
    float* __restrict__ out, float* __restrict__ out2)
{
  const int row = blockIdx.x, tid = threadIdx.x;
  float2 x = *(const float2*)&in[(size_t)row * DMODEL + tid * 2];
  float s = x.x + x.y, sq = x.x * x.x + x.y * x.y;
#pragma unroll
  for (int off = 32; off > 0; off >>= 1) {
    s += __shfl_down(s, off);
    sq += __shfl_down(sq, off);
  }
  __shared__ float ps[4], pq[4];
  __shared__ float smu, srv;
  const int wv = tid >> 6, ln = tid & 63;
  if (ln == 0) { ps[wv] = s; pq[wv] = sq; }
  __syncthreads();
  if (tid == 0) {
    float S = ps[0] + ps[1] + ps[2] + ps[3];
    float Q = pq[0] + pq[1] + pq[2] + pq[3];
    float mu = S / 512.f;
    float var = Q / 512.f - mu * mu;
    smu = mu;
    srv = 1.0f / sqrtf(var + 1e-5f);
  }
  __syncthreads();
  const float mu = smu, rv = srv;
  const int c = tid * 2;
  float y0 = (x.x - mu) * rv * g[c] + bb[c];
  float y1 = (x.y - mu) * rv * g[c + 1] + bb[c + 1];
  out[(size_t)row * DMODEL + c] = y0;
  out[(size_t)row * DMODEL + c + 1] = y1;
  if (out2) {
    out2[(size_t)row * DMODEL + c] = y0;
    out2[(size_t)row * DMODEL + c + 1] = y1;
  }
}

// ---------------- gating ----------------
__global__ __launch_bounds__(64) void zero_cnt_kernel(int* __restrict__ cnt)
{
  if (threadIdx.x < NEXP) cnt[threadIdx.x] = 0;
}

__global__ __launch_bounds__(256) void gate_kernel(
    const float* __restrict__ h1, const float* __restrict__ gw, const float* __restrict__ gb,
    int* __restrict__ cnt, int* __restrict__ toks, float* __restrict__ gws)
{
  const int wv = threadIdx.x >> 6, ln = threadIdx.x & 63;
  const int tok = blockIdx.x * 4 + wv;
  const float* hr = h1 + (size_t)tok * DMODEL;
  float p0 = 0, p1 = 0, p2 = 0, p3 = 0;
#pragma unroll
  for (int k = 0; k < 8; ++k) {
    float xv = hr[ln + 64 * k];
    p0 += xv * gw[0 * DMODEL + ln + 64 * k];
    p1 += xv * gw[1 * DMODEL + ln + 64 * k];
    p2 += xv * gw[2 * DMODEL + ln + 64 * k];
    p3 += xv * gw[3 * DMODEL + ln + 64 * k];
  }
#pragma unroll
  for (int off = 32; off > 0; off >>= 1) {
    p0 += __shfl_down(p0, off);
    p1 += __shfl_down(p1, off);
    p2 += __shfl_down(p2, off);
    p3 += __shfl_down(p3, off);
  }
  if (ln == 0) {
    p0 += gb[0]; p1 += gb[1]; p2 += gb[2]; p3 += gb[3];
    int i0 = 0; float v0 = p0;
    if (p1 > v0) { v0 = p1; i0 = 1; }
    if (p2 > v0) { v0 = p2; i0 = 2; }
    if (p3 > v0) { v0 = p3; i0 = 3; }
    int i1 = -1; float v1 = NEG_INF;
    if (i0 != 0 && p0 > v1) { v1 = p0; i1 = 0; }
    if (i0 != 1 && p1 > v1) { v1 = p1; i1 = 1; }
    if (i0 != 2 && p2 > v1) { v1 = p2; i1 = 2; }
    if (i0 != 3 && p3 > v1) { v1 = p3; i1 = 3; }
    float e = expf(v1 - v0);
    float w0 = 1.f / (1.f + e);
    float w1 = e / (1.f + e);
    int pos0 = atomicAdd(&cnt[i0], 1);
    toks[i0 * NTOK + pos0] = tok;
    gws[i0 * NTOK + pos0] = w0;
    int pos1 = atomicAdd(&cnt[i1], 1);
    toks[i1 * NTOK + pos1] = tok;
    gws[i1 * NTOK + pos1] = w1;
  }
}

// ---------------- weight transpose + fp32->fp16 ----------------
__global__ __launch_bounds__(256) void transpose_f16_kernel(
    const float* __restrict__ in, _Float16* __restrict__ outp, int R, int C)
{
  __shared__ float tl[32][33];
  const int bid = blockIdx.x;
  const int e  = bid >> 10;
  const int t2 = bid & 1023;
  const int tC = C >> 5;
  const int r0 = (t2 / tC) << 5;
  const int c0 = (t2 % tC) << 5;
  const float* ine  = in   + (size_t)e * R * C;
  _Float16*    oute = outp + (size_t)e * R * C;
  const int ci = threadIdx.x & 31, ri = threadIdx.x >> 5;
#pragma unroll
  for (int i = 0; i < 4; ++i)
    tl[ri + i * 8][ci] = ine[(size_t)(r0 + ri + i * 8) * C + c0 + ci];
  __syncthreads();
  const int rr = threadIdx.x & 31, cc = threadIdx.x >> 5;
#pragma unroll
  for (int i = 0; i < 4; ++i)
    oute[(size_t)(c0 + cc + i * 8) * R + r0 + rr] = (_Float16)tl[rr][cc + i * 8];
}

// ---------------- grouped MoE via fp16 MFMA, square-blocked ----------------------------
__global__ __launch_bounds__(512) void moe_mfma_kernel(
    const float* __restrict__ h1, const _Float16* __restrict__ w1t, const float* __restrict__ b1,
    const _Float16* __restrict__ w2t, const float* __restrict__ b2,
    const int* __restrict__ cnt, const int* __restrict__ toks, const float* __restrict__ gws,
    float* __restrict__ Z)
{
  __shared__ _Float16 t_lds[64 * 520];
  __shared__ _Float16 hm[64 * 264];
  __shared__ int   tk_s[64];
  __shared__ float gw_s[64];
  const int tid = threadIdx.x;
  const int e = blockIdx.x >> 10;
  const int tile = blockIdx.x & 1023;
  const int cn = cnt[e];
  if (tile * 64 >= cn) return;
  if (tid < 64) {
    int idx = tile * 64 + tid;
    if (idx < cn) { tk_s[tid] = toks[e * NTOK + idx]; gw_s[tid] = gws[e * NTOK + idx]; }
    else          { tk_s[tid] = -1;                   gw_s[tid] = 0.f; }
  }
  __syncthreads();
  for (int it = tid; it < 64 * 128; it += 512) {
    int r = it >> 7, c4 = (it & 127) * 4;
    int tk = tk_s[r];
    float4 v = make_float4(0.f, 0.f, 0.f, 0.f);
    if (tk >= 0) v = *(const float4*)&h1[(size_t)tk * DMODEL + c4];
    _Float16* p = &t_lds[r * 520 + c4];
    p[0] = (_Float16)v.x; p[1] = (_Float16)v.y; p[2] = (_Float16)v.z; p[3] = (_Float16)v.w;
  }
  __syncthreads();

  const int w = tid >> 6, l = tid & 63;
  const int lr = l & 15, lg = l >> 4;
  const _Float16* w1e = w1t + (size_t)e * NDFF * DMODEL;
  const _Float16* w2e = w2t + (size_t)e * DMODEL * NDFF;
  const float* b1e = b1 + e * NDFF;

  f32x4 acc2[4][4];
#pragma unroll
  for (int mt = 0; mt < 4; ++mt)
#pragma unroll
    for (int nt = 0; nt < 4; ++nt) acc2[mt][nt] = (f32x4){0.f, 0.f, 0.f, 0.f};

  for (int fc = 0; fc < 8; ++fc) {
    f32x4 acc1[4][2];
#pragma unroll
    for (int mt = 0; mt < 4; ++mt)
#pragma unroll
      for (int nt1 = 0; nt1 < 2; ++nt1) acc1[mt][nt1] = (f32x4){0.f, 0.f, 0.f, 0.f};
#pragma unroll
    for (int ks = 0; ks < 16; ++ks) {
      half8 am[4];
#pragma unroll
      for (int mt = 0; mt < 4; ++mt)
        am[mt] = *(const half8*)&t_lds[(mt * 16 + lr) * 520 + ks * 32 + lg * 8];
#pragma unroll
      for (int nt1 = 0; nt1 < 2; ++nt1) {
        half8 bfr = *(const half8*)&w1e[(size_t)(fc * 256 + w * 32 + nt1 * 16 + lr) * DMODEL + ks * 32 + lg * 8];
#pragma unroll
        for (int mt = 0; mt < 4; ++mt)
          acc1[mt][nt1] = __builtin_amdgcn_mfma_f32_16x16x32_f16(am[mt], bfr, acc1[mt][nt1], 0, 0, 0);
      }
    }
#pragma unroll
    for (int nt1 = 0; nt1 < 2; ++nt1) {
      float b1v = b1e[fc * 256 + w * 32 + nt1 * 16 + lr];
#pragma unroll
      for (int mt = 0; mt < 4; ++mt)
#pragma unroll
        for (int r = 0; r < 4; ++r)
          hm[(mt * 16 + lg * 4 + r) * 264 + w * 32 + nt1 * 16 + lr] =
              (_Float16)fmaxf(acc1[mt][nt1][r] + b1v, 0.f);
    }
    __syncthreads();
#pragma unroll
    for (int ks2 = 0; ks2 < 8; ++ks2) {
      half8 am[4];
#pragma unroll
      for (int mt = 0; mt < 4; ++mt)
        am[mt] = *(const half8*)&hm[(mt * 16 + lr) * 264 + ks2 * 32 + lg * 8];
#pragma unroll
      for (int nt = 0; nt < 4; ++nt) {
        half8 bfr = *(const half8*)&w2e[(size_t)(w * 64 + nt * 16 + lr) * NDFF + fc * 256 + ks2 * 32 + lg * 8];
#pragma unroll
        for (int mt = 0; mt < 4; ++mt)
          acc2[mt][nt] = __builtin_amdgcn_mfma_f32_16x16x32_f16(am[mt], bfr, acc2[mt][nt], 0, 0, 0);
      }
    }
    __syncthreads();
  }

  const float* b2e = b2 + e * DMODEL;
#pragma unroll
  for (int nt = 0; nt < 4; ++nt) {
    float b2v = b2e[w * 64 + nt * 16 + lr];
#pragma unroll
    for (int mt = 0; mt < 4; ++mt) {
#pragma unroll
      for (int r = 0; r < 4; ++r) {
        int row = mt * 16 + lg * 4 + r;
        int tk = tk_s[row];
        if (tk >= 0)
          atomicAdd(&Z[(size_t)tk * DMODEL + w * 64 + nt * 16 + lr],
                    (acc2[mt][nt][r] + b2v) * gw_s[row]);
      }
    }
  }
}

// ---------------- launch ----------------
extern "C" void kernel_launch(void* const* d_in, const int* in_sizes, int n_in,
                              void* d_out, int out_size, void* d_ws, size_t ws_size,
                              hipStream_t stream) {
  const float* x     = (const float*)d_in[0];
  const float* emb_w = (const float*)d_in[1];
  const float* wq    = (const float*)d_in[2];
  const float* bq    = (const float*)d_in[3];
  const float* wk    = (const float*)d_in[4];
  const float* bk    = (const float*)d_in[5];
  const float* wv    = (const float*)d_in[6];
  const float* bv    = (const float*)d_in[7];
  const float* wo    = (const float*)d_in[8];
  const float* bo    = (const float*)d_in[9];
  const float* proj  = (const float*)d_in[10];
  const float* ln2g  = (const float*)d_in[11];
  const float* ln2b  = (const float*)d_in[12];
  const float* ln3g  = (const float*)d_in[13];
  const float* ln3b  = (const float*)d_in[14];
  const float* gatew = (const float*)d_in[15];
  const float* gateb = (const float*)d_in[16];
  const float* w1    = (const float*)d_in[17];
  const float* b1    = (const float*)d_in[18];
  const float* w2    = (const float*)d_in[19];
  const float* b2    = (const float*)d_in[20];
  float* out = (float*)d_out;
  float* ws  = (float*)d_ws;

  if (ws_size < F_END * sizeof(float)) {
    fallback_zero_kernel<<<NTOK * 2, 256, 0, stream>>>(out);
    return;
  }

  float* BUF1 = ws + F_BUF1;   // K -> Q -> pre -> Z
  float* BUF2 = out;           // V -> attn -> h1 (d_out reused as scratch)
  int*   cnt  = (int*)(ws + F_CNTI);
  int*   toks = (int*)(ws + F_TOKI);
  float* gwf  = ws + F_GWF;
  _Float16* w1t = (_Float16*)(ws + F_CTX);                  // [E][2048][512] (after attn)
  _Float16* w2t = w1t + (size_t)NEXP * NDFF * DMODEL;       // [E][512][2048]

  zero_cnt_kernel<<<1, 64, 0, stream>>>(cnt);
  proj_pack_kernel<<<80, 256, 0, stream>>>(proj, ws + F_PJT);
  effmat_kernel<<<1536, 128, 0, stream>>>(wq, wk, wv, emb_w, ws + F_EFF);
  // K = x @ Keff^T + bk -> BUF1
  gemm_nt_kernel<<<4096, 256, 0, stream>>>(x, ws + F_EFF + 65536, CIN, nullptr, nullptr, 0, bk, BUF1, DMODEL, 8);
  // V = x @ Veff^T + bv -> BUF2 (d_out)
  gemm_nt_kernel<<<4096, 256, 0, stream>>>(x, ws + F_EFF + 131072, CIN, nullptr, nullptr, 0, bv, BUF2, DMODEL, 8);
  kdash_max_kernel<<<512, 1024, 0, stream>>>(BUF1, ws + F_PJT, ws + F_PART);
  reduce_max_kernel<<<1, 256, 0, stream>>>(ws + F_PART, ws + F_STAB, 512);
  ctx_kernel<<<256, 1024, 0, stream>>>(BUF1, BUF2, ws + F_PJT, ws + F_STAB, ws + F_CTX, ws + F_KSUM);
  // Q = x @ Qeff^T + bq -> BUF1 (K dead)
  gemm_nt_kernel<<<4096, 256, 0, stream>>>(x, ws + F_EFF, CIN, nullptr, nullptr, 0, bq, BUF1, DMODEL, 8);
  attn_kernel<<<4096, 1024, 0, stream>>>(BUF1, ws + F_CTX, ws + F_KSUM, ws + F_PJT, BUF2);
  // ctx now dead: build fp16 transposed weights in its place
  transpose_f16_kernel<<<4096, 256, 0, stream>>>(w1, w1t, DMODEL, NDFF);   // w1t[e][f][k]
  transpose_f16_kernel<<<4096, 256, 0, stream>>>(w2, w2t, NDFF, DMODEL);   // w2t[e][n][f]
  // pre = attn@wo^T + x@emb_w^T + bo -> BUF1
  gemm_nt_kernel<<<4096, 256, 0, stream>>>(BUF2, wo, DMODEL, x, emb_w, CIN, bo, BUF1, DMODEL, 8);
  // h1 = LN(pre) -> BUF2; Z = h1 -> BUF1
  ln_kernel<<<NTOK, 256, 0, stream>>>(BUF1, ln2g, ln2b, BUF2, BUF1);
  gate_kernel<<<8192, 256, 0, stream>>>(BUF2, gatew, gateb, cnt, toks, gwf);
  moe_mfma_kernel<<<4096, 512, 0, stream>>>(BUF2, w1t, b1, w2t, b2, cnt, toks, gwf, BUF1);
  ln_kernel<<<NTOK, 256, 0, stream>>>(BUF1, ln3g, ln3b, out, nullptr);
}

// Round 6
// 4642.639 us; speedup vs baseline: 1.1334x; 1.1334x over previous
//
#include <hip/hip_runtime.h>
#include <math.h>

// Problem dims
#define NBATCH 32
#define NPOS   1024
#define NTOK   32768          // NBATCH*NPOS
#define DMODEL 512
#define NHEAD  8
#define DHD    64
#define MMR    266            // random-feature count
#define NDFF   2048
#define NEXP   4
#define CIN    128            // PL*CIN = flattened patch dim

#define DNSC   0.35355339059327373f   // 64^-0.25
#define RSM    0.06131393394849658f   // 266^-0.5
#define NEG_INF -3.0e38f

typedef _Float16 half8 __attribute__((ext_vector_type(8)));
typedef _Float16 half4 __attribute__((ext_vector_type(4)));
typedef float    f32x4 __attribute__((ext_vector_type(4)));

// ---------------- workspace layout (float offsets) ----------------
static const size_t F_BUF1 = 0;          // 16777216 (K -> Q -> pre -> Z)
static const size_t F_CTX  = 16777216;   // 4358144 (256*266*64); reused for fp16 weights after attn
static const size_t F_KSUM = 21135360;   // 68096 (256*266)
static const size_t F_PART = 21203456;   // 2048
static const size_t F_STAB = 21205504;   // 16
static const size_t F_EFF  = 21205520;   // 3*512*128 = 196608
static const size_t F_CNTI = 21402128;   // 16 (ints)
static const size_t F_TOKI = 21402144;   // 4*32768 ints
static const size_t F_GWF  = 21533216;   // 4*32768 floats
static const size_t F_PJT  = 21664288;   // 20480 floats: packed proj [64][16][20]
static const size_t F_END  = 21684768;

// 17-term register accumulate from the packed proj fragment
#define DASH17(da, q) \
  da[0]+=q*pA.x; da[1]+=q*pA.y; da[2]+=q*pA.z; da[3]+=q*pA.w; \
  da[4]+=q*pB.x; da[5]+=q*pB.y; da[6]+=q*pB.z; da[7]+=q*pB.w; \
  da[8]+=q*pC.x; da[9]+=q*pC.y; da[10]+=q*pC.z; da[11]+=q*pC.w; \
  da[12]+=q*pD.x; da[13]+=q*pD.y; da[14]+=q*pD.z; da[15]+=q*pD.w; \
  da[16]+=q*pE;

// ---------------- fallback (ws too small): write zeros, fail cleanly -----------
__global__ __launch_bounds__(256) void fallback_zero_kernel(float* __restrict__ out) {
  out[(size_t)blockIdx.x * 256 + threadIdx.x] = 0.f;
}

// ---------------- pack proj: projT[d*320 + g*20 + j] = proj[(g*17+j)*64 + d] ----------
__global__ __launch_bounds__(256) void proj_pack_kernel(
    const float* __restrict__ proj, float* __restrict__ projT)
{
  int idx = blockIdx.x * 256 + threadIdx.x;
  if (idx >= 20480) return;
  int d = idx / 320, rem = idx % 320;
  int g = rem / 20, j = rem % 20;
  int m = g * 17 + j;
  projT[idx] = (j < 17 && m < MMR) ? proj[m * 64 + d] : 0.f;
}

// ---------------- effective QKV matrices: eff[mat] = W[mat] @ emb_w  (512x128) ----------
__global__ __launch_bounds__(128) void effmat_kernel(
    const float* __restrict__ wq, const float* __restrict__ wk, const float* __restrict__ wv,
    const float* __restrict__ emb, float* __restrict__ eff)
{
  __shared__ float wrow[512];
  const int bid = blockIdx.x;          // 0..1535
  const int mat = bid >> 9;
  const int n   = bid & 511;
  const float* W = (mat == 0) ? wq : ((mat == 1) ? wk : wv);
  const int tid = threadIdx.x;         // 128
  for (int i = tid; i < 512; i += 128) wrow[i] = W[n * 512 + i];
  __syncthreads();
  float acc = 0.f;
  for (int d = 0; d < 512; ++d) acc += wrow[d] * emb[d * CIN + tid];
  eff[mat * 65536 + n * CIN + tid] = acc;
}

// ------- generic GEMM: C = A(MxK)*W(NxK)^T [+ A2(MxK2)*W2(NxK2)^T] + bias --------------
__global__ __launch_bounds__(256) void gemm_nt_kernel(
    const float* __restrict__ A, const float* __restrict__ W, int K,
    const float* __restrict__ A2, const float* __restrict__ W2, int K2,
    const float* __restrict__ bias, float* __restrict__ C, int N, int ncb)
{
  __shared__ float As[32][64];
  __shared__ float Ws[32][64];
  const int tid  = threadIdx.x;
  const int bx   = blockIdx.x % ncb;
  const int by   = blockIdx.x / ncb;
  const int row0 = by * 64, col0 = bx * 64;
  const int tx   = tid & 15, ty = tid >> 4;
  const int lr   = tid >> 3;
  const int lk   = (tid & 7) * 4;
  float acc[4][4] = {};
  for (int pass = 0; pass < 2; ++pass) {
    const float* Ap = pass ? A2 : A;
    const float* Wp = pass ? W2 : W;
    const int    Kp = pass ? K2 : K;
    if (!Ap) continue;
    for (int k0 = 0; k0 < Kp; k0 += 32) {
      __syncthreads();
#pragma unroll
      for (int rr = 0; rr < 2; ++rr) {
        const int r = lr + rr * 32;
        float4 a4 = *(const float4*)&Ap[(size_t)(row0 + r) * Kp + k0 + lk];
        As[lk + 0][r] = a4.x; As[lk + 1][r] = a4.y; As[lk + 2][r] = a4.z; As[lk + 3][r] = a4.w;
        float4 w4 = *(const float4*)&Wp[(size_t)(col0 + r) * Kp + k0 + lk];
        Ws[lk + 0][r] = w4.x; Ws[lk + 1][r] = w4.y; Ws[lk + 2][r] = w4.z; Ws[lk + 3][r] = w4.w;
      }
      __syncthreads();
#pragma unroll
      for (int kk = 0; kk < 32; ++kk) {
        float4 av = *(const float4*)&As[kk][ty * 4];
        float4 wv = *(const float4*)&Ws[kk][tx * 4];
        acc[0][0] += av.x * wv.x; acc[0][1] += av.x * wv.y; acc[0][2] += av.x * wv.z; acc[0][3] += av.x * wv.w;
        acc[1][0] += av.y * wv.x; acc[1][1] += av.y * wv.y; acc[1][2] += av.y * wv.z; acc[1][3] += av.y * wv.w;
        acc[2][0] += av.z * wv.x; acc[2][1] += av.z * wv.y; acc[2][2] += av.z * wv.z; acc[2][3] += av.z * wv.w;
        acc[3][0] += av.w * wv.x; acc[3][1] += av.w * wv.y; acc[3][2] += av.w * wv.z; acc[3][3] += av.w * wv.w;
      }
    }
  }
#pragma unroll
  for (int i = 0; i < 4; ++i) {
    const int row = row0 + ty * 4 + i;
    const int col = col0 + tx * 4;
    float4 o = make_float4(acc[i][0], acc[i][1], acc[i][2], acc[i][3]);
    if (bias) {
      float4 b4 = *(const float4*)&bias[col];
      o.x += b4.x; o.y += b4.y; o.z += b4.z; o.w += b4.w;
    }
    *(float4*)&C[(size_t)row * N + col] = o;
  }
}

// ---------------- global max of k-dash: 512 thr, 512 rows/block, 16-row chunks ----------
__global__ __launch_bounds__(512, 2) void kdash_max_kernel(
    const float* __restrict__ Kbuf, const float* __restrict__ projT, float* __restrict__ partial)
{
  __shared__ float pjG[20480];
  __shared__ float kl[16 * 68];
  __shared__ float red[512];
  const int tid = threadIdx.x;
  for (int i4 = tid; i4 < 5120; i4 += 512)
    ((float4*)pjG)[i4] = ((const float4*)projT)[i4];
  const int w = tid >> 6, l = tid & 63;
  const int ml = l & 15, ds = l >> 4;
  const int dbase = ds * 16;
  const int r0 = 2 * w;
  float mxl = NEG_INF;
  for (int t = 0; t < 32; ++t) {
    __syncthreads();
    for (int idx = tid; idx < 1024; idx += 512) {
      int r = idx >> 6, dd = idx & 63;
      kl[r * 68 + dd] = Kbuf[((size_t)blockIdx.x * 512 + t * 16 + r) * 64 + dd] * DNSC;
    }
    __syncthreads();
    float da0[17], da1[17];
#pragma unroll
    for (int j = 0; j < 17; ++j) { da0[j] = 0.f; da1[j] = 0.f; }
    for (int dd = 0; dd < 16; ++dd) {
      int d = dbase + dd;
      float q0 = kl[r0 * 68 + d], q1 = kl[r0 * 68 + 68 + d];
      const float* pr = &pjG[d * 320 + ml * 20];
      float4 pA = *(const float4*)pr, pB = *(const float4*)(pr + 4),
             pC = *(const float4*)(pr + 8), pD = *(const float4*)(pr + 12);
      float pE = pr[16];
      DASH17(da0, q0)
      DASH17(da1, q1)
    }
#pragma unroll
    for (int j = 0; j < 17; ++j) {
      da0[j] += __shfl_xor(da0[j], 16); da0[j] += __shfl_xor(da0[j], 32);
      da1[j] += __shfl_xor(da1[j], 16); da1[j] += __shfl_xor(da1[j], 32);
    }
#pragma unroll
    for (int j = 0; j < 17; ++j) {
      int m = ml * 17 + j;
      if (m < MMR) { mxl = fmaxf(mxl, da0[j]); mxl = fmaxf(mxl, da1[j]); }
    }
  }
  red[tid] = mxl;
  __syncthreads();
  for (int st = 256; st > 0; st >>= 1) {
    if (tid < st) red[tid] = fmaxf(red[tid], red[tid + st]);
    __syncthreads();
  }
  if (tid == 0) partial[blockIdx.x] = red[0];
}

__global__ __launch_bounds__(256) void reduce_max_kernel(
    const float* __restrict__ part, float* __restrict__ stab, int n)
{
  __shared__ float red[256];
  float m = NEG_INF;
  for (int i = threadIdx.x; i < n; i += 256) m = fmaxf(m, part[i]);
  red[threadIdx.x] = m;
  __syncthreads();
  for (int st = 128; st > 0; st >>= 1) {
    if (threadIdx.x < st) red[threadIdx.x] = fmaxf(red[threadIdx.x], red[threadIdx.x + st]);
    __syncthreads();
  }
  if (threadIdx.x == 0) stab[0] = red[0];
}

// ---------------- ctx = kp^T @ v, ksum = sum kp; one (b,h)/block, 512 thr ----------
__global__ __launch_bounds__(512, 2) void ctx_kernel(
    const float* __restrict__ Kbuf, const float* __restrict__ Vbuf,
    const float* __restrict__ projT, const float* __restrict__ stabp,
    float* __restrict__ ctxg, float* __restrict__ ksumg)
{
  __shared__ float pjG[20480];
  __shared__ float kl[16 * 68];
  __shared__ float vl[16 * 68];
  __shared__ _Float16 kp16[16 * 512];   // 16 rows x (16 groups x 32-pad)
  __shared__ float ks[272];
  const int tid = threadIdx.x;
  const int bh = blockIdx.x;
  const int b = bh >> 3, h = bh & 7;
  const float stab = stabp[0];
  for (int i4 = tid; i4 < 5120; i4 += 512)
    ((float4*)pjG)[i4] = ((const float4*)projT)[i4];
  if (tid < 272) ks[tid] = 0.f;
  const int w = tid >> 6, l = tid & 63;
  const int ml = l & 15, ds = l >> 4;
  const int dbase = ds * 16;
  const int r0 = 2 * w;
  const int jh = ds >> 1, rsel = ds & 1;
  const int d = l;
  // ksum mapping for tid<272: m=tid -> group g, in-group j
  const int ksg = tid / 17, ksj = tid - ksg * 17;
  float acc[2][17];
#pragma unroll
  for (int g = 0; g < 2; ++g)
#pragma unroll
    for (int j = 0; j < 17; ++j) acc[g][j] = 0.f;

  for (int t = 0; t < 64; ++t) {
    __syncthreads();
    for (int idx = tid; idx < 1024; idx += 512) {
      int r = idx >> 6, dd = idx & 63;
      size_t gg = ((size_t)(b * NPOS + t * 16 + r)) * DMODEL + h * DHD + dd;
      kl[r * 68 + dd] = Kbuf[gg] * DNSC;
      vl[r * 68 + dd] = Vbuf[gg];
    }
    __syncthreads();
    // dash for rows r0, r0+1 (partial over d-quarter, reduce over ds)
    float da0[17], da1[17]; float dg0 = 0.f, dg1 = 0.f;
#pragma unroll
    for (int j = 0; j < 17; ++j) { da0[j] = 0.f; da1[j] = 0.f; }
    for (int dd = 0; dd < 16; ++dd) {
      int dq = dbase + dd;
      float q0 = kl[r0 * 68 + dq], q1 = kl[r0 * 68 + 68 + dq];
      const float* pr = &pjG[dq * 320 + ml * 20];
      float4 pA = *(const float4*)pr, pB = *(const float4*)(pr + 4),
             pC = *(const float4*)(pr + 8), pD = *(const float4*)(pr + 12);
      float pE = pr[16];
      dg0 += q0 * q0; dg1 += q1 * q1;
      DASH17(da0, q0)
      DASH17(da1, q1)
    }
#pragma unroll
    for (int j = 0; j < 17; ++j) {
      da0[j] += __shfl_xor(da0[j], 16); da0[j] += __shfl_xor(da0[j], 32);
      da1[j] += __shfl_xor(da1[j], 16); da1[j] += __shfl_xor(da1[j], 32);
    }
    dg0 += __shfl_xor(dg0, 16); dg0 += __shfl_xor(dg0, 32);
    dg1 += __shfl_xor(dg1, 16); dg1 += __shfl_xor(dg1, 32);
    // exp: lane handles row r0+rsel, strided j = 2k+jh
    float dgx = rsel ? dg1 : dg0;
    const int irow = r0 + rsel;
#pragma unroll
    for (int k = 0; k < 9; ++k) {
      int j = 2 * k + jh;
      if (j < 17) {
        int m = ml * 17 + j;
        float dv = rsel ? da1[j] : da0[j];
        float v = 0.f;
        if (m < MMR) v = RSM * (expf(dv - 0.5f * dgx - stab) + 1e-4f);
        kp16[irow * 512 + ml * 32 + j] = (_Float16)v;
      }
    }
    __syncthreads();
    // ksum accumulation: thread tid<272 owns m=tid
    if (tid < 272) {
      float s = 0.f;
      const _Float16* kb = &kp16[ksg * 32 + ksj];
#pragma unroll
      for (int i = 0; i < 16; ++i) s += (float)kb[i * 512];
      ks[tid] += s;
    }
    // PV: wave owns m-groups {2w, 2w+1}; lane owns output dim d
    for (int i = 0; i < 16; ++i) {
      float vv = vl[i * 68 + d];
#pragma unroll
      for (int g = 0; g < 2; ++g) {
        const _Float16* kr = &kp16[i * 512 + (2 * w + g) * 32];
        half8 kA = *(const half8*)kr;
        half8 kB = *(const half8*)(kr + 8);
        float kE = (float)kr[16];
        acc[g][0] += (float)kA[0] * vv; acc[g][1] += (float)kA[1] * vv;
        acc[g][2] += (float)kA[2] * vv; acc[g][3] += (float)kA[3] * vv;
        acc[g][4] += (float)kA[4] * vv; acc[g][5] += (float)kA[5] * vv;
        acc[g][6] += (float)kA[6] * vv; acc[g][7] += (float)kA[7] * vv;
        acc[g][8] += (float)kB[0] * vv; acc[g][9] += (float)kB[1] * vv;
        acc[g][10] += (float)kB[2] * vv; acc[g][11] += (float)kB[3] * vv;
        acc[g][12] += (float)kB[4] * vv; acc[g][13] += (float)kB[5] * vv;
        acc[g][14] += (float)kB[6] * vv; acc[g][15] += (float)kB[7] * vv;
        acc[g][16] += kE * vv;
      }
    }
  }
  const size_t cb = (size_t)bh * MMR * DHD;
#pragma unroll
  for (int g = 0; g < 2; ++g)
#pragma unroll
    for (int j = 0; j < 17; ++j) {
      int m = (2 * w + g) * 17 + j;
      if (m < MMR) ctxg[cb + (size_t)m * 64 + d] = acc[g][j];
    }
  if (tid < MMR) ksumg[bh * MMR + tid] = ks[tid];
}

// ---------------- attn = (qp @ ctx)/den; 512 thr, 32 rows/block ----------------
__global__ __launch_bounds__(512, 2) void attn_kernel(
    const float* __restrict__ Qbuf, const float* __restrict__ ctxg,
    const float* __restrict__ ksumg, const float* __restrict__ projT,
    float* __restrict__ attnb)
{
  __shared__ float pjG[20480];
  __shared__ float ql[32 * 68];
  __shared__ _Float16 qp16[32 * 512];
  __shared__ float ks[272];
  __shared__ float den_s[32];
  const int tid = threadIdx.x;
  const int bh = blockIdx.x >> 5;
  const int n0 = (blockIdx.x & 31) * 32;
  const int b = bh >> 3, h = bh & 7;
  for (int i4 = tid; i4 < 5120; i4 += 512)
    ((float4*)pjG)[i4] = ((const float4*)projT)[i4];
  if (tid < 272) ks[tid] = (tid < MMR) ? ksumg[bh * MMR + tid] : 0.f;
  for (int idx = tid; idx < 2048; idx += 512) {
    int r = idx >> 6, dd = idx & 63;
    ql[r * 68 + dd] = Qbuf[((size_t)(b * NPOS + n0 + r)) * DMODEL + h * DHD + dd] * DNSC;
  }
  __syncthreads();
  const int w = tid >> 6, l = tid & 63;
  const int ml = l & 15, ds = l >> 4;
  const int dbase = ds * 16;
  const int jh = ds >> 1, rsel = ds & 1;
  for (int s = 0; s < 2; ++s) {
    const int r0 = s * 16 + 2 * w;
    float da0[17], da1[17]; float dg0 = 0.f, dg1 = 0.f;
#pragma unroll
    for (int j = 0; j < 17; ++j) { da0[j] = 0.f; da1[j] = 0.f; }
    for (int dd = 0; dd < 16; ++dd) {
      int dq = dbase + dd;
      float q0 = ql[r0 * 68 + dq], q1 = ql[r0 * 68 + 68 + dq];
      const float* pr = &pjG[dq * 320 + ml * 20];
      float4 pA = *(const float4*)pr, pB = *(const float4*)(pr + 4),
             pC = *(const float4*)(pr + 8), pD = *(const float4*)(pr + 12);
      float pE = pr[16];
      dg0 += q0 * q0; dg1 += q1 * q1;
      DASH17(da0, q0)
      DASH17(da1, q1)
    }
#pragma unroll
    for (int j = 0; j < 17; ++j) {
      da0[j] += __shfl_xor(da0[j], 16); da0[j] += __shfl_xor(da0[j], 32);
      da1[j] += __shfl_xor(da1[j], 16); da1[j] += __shfl_xor(da1[j], 32);
    }
    dg0 += __shfl_xor(dg0, 16); dg0 += __shfl_xor(dg0, 32);
    dg1 += __shfl_xor(dg1, 16); dg1 += __shfl_xor(dg1, 32);
    // per-row max over valid m (reduce over ml lanes)
    float mx0 = NEG_INF, mx1 = NEG_INF;
#pragma unroll
    for (int j = 0; j < 17; ++j) {
      int m = ml * 17 + j;
      if (m < MMR) { mx0 = fmaxf(mx0, da0[j]); mx1 = fmaxf(mx1, da1[j]); }
    }
#pragma unroll
    for (int off = 1; off < 16; off <<= 1) {
      mx0 = fmaxf(mx0, __shfl_xor(mx0, off));
      mx1 = fmaxf(mx1, __shfl_xor(mx1, off));
    }
    float dgx = rsel ? dg1 : dg0;
    float mxx = rsel ? mx1 : mx0;
    const int row = r0 + rsel;
    float dp = 0.f;
#pragma unroll
    for (int k = 0; k < 9; ++k) {
      int j = 2 * k + jh;
      if (j < 17) {
        int m = ml * 17 + j;
        float dv = rsel ? da1[j] : da0[j];
        float v = 0.f;
        if (m < MMR) { v = RSM * (expf(dv - 0.5f * dgx - mxx) + 1e-4f); dp += v * ks[m]; }
        qp16[row * 512 + ml * 32 + j] = (_Float16)v;
      }
    }
    dp += __shfl_xor(dp, 1); dp += __shfl_xor(dp, 2); dp += __shfl_xor(dp, 4);
    dp += __shfl_xor(dp, 8); dp += __shfl_xor(dp, 32);
    if ((l & 47) == 0) den_s[row] = dp;   // lanes 0 (rsel=0) and 16 (rsel=1)
  }
  __syncthreads();
  // PV: wave wg owns 4 rows, lane = output d
  const int wg = tid >> 6, lane = tid & 63;
  float acc[4] = {0.f, 0.f, 0.f, 0.f};
  const float* cb = ctxg + (size_t)bh * MMR * DHD + lane;
  for (int g = 0; g < 16; ++g) {
    float cv[17];
#pragma unroll
    for (int j = 0; j < 17; ++j) cv[j] = cb[(size_t)(g * 17 + j) * 64];
#pragma unroll
    for (int tt = 0; tt < 4; ++tt) {
      const _Float16* qr = &qp16[(wg * 4 + tt) * 512 + g * 32];
      half8 qA = *(const half8*)qr;
      half8 qB = *(const half8*)(qr + 8);
      float qE = (float)qr[16];
      acc[tt] += (float)qA[0] * cv[0] + (float)qA[1] * cv[1] + (float)qA[2] * cv[2]
               + (float)qA[3] * cv[3] + (float)qA[4] * cv[4] + (float)qA[5] * cv[5]
               + (float)qA[6] * cv[6] + (float)qA[7] * cv[7]
               + (float)qB[0] * cv[8] + (float)qB[1] * cv[9] + (float)qB[2] * cv[10]
               + (float)qB[3] * cv[11] + (float)qB[4] * cv[12] + (float)qB[5] * cv[13]
               + (float)qB[6] * cv[14] + (float)qB[7] * cv[15]
               + qE * cv[16];
    }
  }
#pragma unroll
  for (int tt = 0; tt < 4; ++tt) {
    int r = wg * 4 + tt;
    attnb[((size_t)(b * NPOS + n0 + r)) * DMODEL + h * DHD + lane] = acc[tt] / den_s[r];
  }
}

// ---------------- LayerNorm (one block per row); optional second output ----------------
__global__ __launch_bounds__(256) void ln_kernel(
    const float* __restrict__ in, const float* __restrict__ g, const float* __restrict__ bb,
    float* __restrict__ out, float* __restrict__ out2)
{
  const int row = blockIdx.x, tid = threadIdx.x;
  float2 x = *(const float2*)&in[(size_t)row * DMODEL + tid * 2];
  float s = x.x + x.y, sq = x.x * x.x + x.y * x.y;
#pragma unroll
  for (int off = 32; off > 0; off >>= 1) {
    s += __shfl_down(s, off);
    sq += __shfl_down(sq, off);
  }
  __shared__ float ps[4], pq[4];
  __shared__ float smu, srv;
  const int wv = tid >> 6, ln = tid & 63;
  if (ln == 0) { ps[wv] = s; pq[wv] = sq; }
  __syncthreads();
  if (tid == 0) {
    float S = ps[0] + ps[1] + ps[2] + ps[3];
    float Q = pq[0] + pq[1] + pq[2] + pq[3];
    float mu = S / 512.f;
    float var = Q / 512.f - mu * mu;
    smu = mu;
    srv = 1.0f / sqrtf(var + 1e-5f);
  }
  __syncthreads();
  const float mu = smu, rv = srv;
  const int c = tid * 2;
  float y0 = (x.x - mu) * rv * g[c] + bb[c];
  float y1 = (x.y - mu) * rv * g[c + 1] + bb[c + 1];
  out[(size_t)row * DMODEL + c] = y0;
  out[(size_t)row * DMODEL + c + 1] = y1;
  if (out2) {
    out2[(size_t)row * DMODEL + c] = y0;
    out2[(size_t)row * DMODEL + c + 1] = y1;
  }
}

// ---------------- gating ----------------
__global__ __launch_bounds__(64) void zero_cnt_kernel(int* __restrict__ cnt)
{
  if (threadIdx.x < NEXP) cnt[threadIdx.x] = 0;
}

__global__ __launch_bounds__(256) void gate_kernel(
    const float* __restrict__ h1, const float* __restrict__ gw, const float* __restrict__ gb,
    int* __restrict__ cnt, int* __restrict__ toks, float* __restrict__ gws)
{
  const int wv = threadIdx.x >> 6, ln = threadIdx.x & 63;
  const int tok = blockIdx.x * 4 + wv;
  const float* hr = h1 + (size_t)tok * DMODEL;
  float p0 = 0, p1 = 0, p2 = 0, p3 = 0;
#pragma unroll
  for (int k = 0; k < 8; ++k) {
    float xv = hr[ln + 64 * k];
    p0 += xv * gw[0 * DMODEL + ln + 64 * k];
    p1 += xv * gw[1 * DMODEL + ln + 64 * k];
    p2 += xv * gw[2 * DMODEL + ln + 64 * k];
    p3 += xv * gw[3 * DMODEL + ln + 64 * k];
  }
#pragma unroll
  for (int off = 32; off > 0; off >>= 1) {
    p0 += __shfl_down(p0, off);
    p1 += __shfl_down(p1, off);
    p2 += __shfl_down(p2, off);
    p3 += __shfl_down(p3, off);
  }
  if (ln == 0) {
    p0 += gb[0]; p1 += gb[1]; p2 += gb[2]; p3 += gb[3];
    int i0 = 0; float v0 = p0;
    if (p1 > v0) { v0 = p1; i0 = 1; }
    if (p2 > v0) { v0 = p2; i0 = 2; }
    if (p3 > v0) { v0 = p3; i0 = 3; }
    int i1 = -1; float v1 = NEG_INF;
    if (i0 != 0 && p0 > v1) { v1 = p0; i1 = 0; }
    if (i0 != 1 && p1 > v1) { v1 = p1; i1 = 1; }
    if (i0 != 2 && p2 > v1) { v1 = p2; i1 = 2; }
    if (i0 != 3 && p3 > v1) { v1 = p3; i1 = 3; }
    float e = expf(v1 - v0);
    float w0 = 1.f / (1.f + e);
    float w1 = e / (1.f + e);
    int pos0 = atomicAdd(&cnt[i0], 1);
    toks[i0 * NTOK + pos0] = tok;
    gws[i0 * NTOK + pos0] = w0;
    int pos1 = atomicAdd(&cnt[i1], 1);
    toks[i1 * NTOK + pos1] = tok;
    gws[i1 * NTOK + pos1] = w1;
  }
}

// ---------------- weight transpose + fp32->fp16 ----------------
__global__ __launch_bounds__(256) void transpose_f16_kernel(
    const float* __restrict__ in, _Float16* __restrict__ outp, int R, int C)
{
  __shared__ float tl[32][33];
  const int bid = blockIdx.x;
  const int e  = bid >> 10;
  const int t2 = bid & 1023;
  const int tC = C >> 5;
  const int r0 = (t2 / tC) << 5;
  const int c0 = (t2 % tC) << 5;
  const float* ine  = in   + (size_t)e * R * C;
  _Float16*    oute = outp + (size_t)e * R * C;
  const int ci = threadIdx.x & 31, ri = threadIdx.x >> 5;
#pragma unroll
  for (int i = 0; i < 4; ++i)
    tl[ri + i * 8][ci] = ine[(size_t)(r0 + ri + i * 8) * C + c0 + ci];
  __syncthreads();
  const int rr = threadIdx.x & 31, cc = threadIdx.x >> 5;
#pragma unroll
  for (int i = 0; i < 4; ++i)
    oute[(size_t)(c0 + cc + i * 8) * R + r0 + rr] = (_Float16)tl[rr][cc + i * 8];
}

// ---------------- grouped MoE via fp16 MFMA, square-blocked ----------------------------
__global__ __launch_bounds__(512) void moe_mfma_kernel(
    const float* __restrict__ h1, const _Float16* __restrict__ w1t, const float* __restrict__ b1,
    const _Float16* __restrict__ w2t, const float* __restrict__ b2,
    const int* __restrict__ cnt, const int* __restrict__ toks, const float* __restrict__ gws,
    float* __restrict__ Z)
{
  __shared__ _Float16 t_lds[64 * 520];
  __shared__ _Float16 hm[64 * 264];
  __shared__ int   tk_s[64];
  __shared__ float gw_s[64];
  const int tid = threadIdx.x;
  const int e = blockIdx.x >> 10;
  const int tile = blockIdx.x & 1023;
  const int cn = cnt[e];
  if (tile * 64 >= cn) return;
  if (tid < 64) {
    int idx = tile * 64 + tid;
    if (idx < cn) { tk_s[tid] = toks[e * NTOK + idx]; gw_s[tid] = gws[e * NTOK + idx]; }
    else          { tk_s[tid] = -1;                   gw_s[tid] = 0.f; }
  }
  __syncthreads();
  for (int it = tid; it < 64 * 128; it += 512) {
    int r = it >> 7, c4 = (it & 127) * 4;
    int tk = tk_s[r];
    float4 v = make_float4(0.f, 0.f, 0.f, 0.f);
    if (tk >= 0) v = *(const float4*)&h1[(size_t)tk * DMODEL + c4];
    _Float16* p = &t_lds[r * 520 + c4];
    p[0] = (_Float16)v.x; p[1] = (_Float16)v.y; p[2] = (_Float16)v.z; p[3] = (_Float16)v.w;
  }
  __syncthreads();

  const int w = tid >> 6, l = tid & 63;
  const int lr = l & 15, lg = l >> 4;
  const _Float16* w1e = w1t + (size_t)e * NDFF * DMODEL;
  const _Float16* w2e = w2t + (size_t)e * DMODEL * NDFF;
  const float* b1e = b1 + e * NDFF;

  f32x4 acc2[4][4];
#pragma unroll
  for (int mt = 0; mt < 4; ++mt)
#pragma unroll
    for (int nt = 0; nt < 4; ++nt) acc2[mt][nt] = (f32x4){0.f, 0.f, 0.f, 0.f};

  for (int fc = 0; fc < 8; ++fc) {
    f32x4 acc1[4][2];
#pragma unroll
    for (int mt = 0; mt < 4; ++mt)
#pragma unroll
      for (int nt1 = 0; nt1 < 2; ++nt1) acc1[mt][nt1] = (f32x4){0.f, 0.f, 0.f, 0.f};
#pragma unroll
    for (int ks = 0; ks < 16; ++ks) {
      half8 am[4];
#pragma unroll
      for (int mt = 0; mt < 4; ++mt)
        am[mt] = *(const half8*)&t_lds[(mt * 16 + lr) * 520 + ks * 32 + lg * 8];
#pragma unroll
      for (int nt1 = 0; nt1 < 2; ++nt1) {
        half8 bfr = *(const half8*)&w1e[(size_t)(fc * 256 + w * 32 + nt1 * 16 + lr) * DMODEL + ks * 32 + lg * 8];
#pragma unroll
        for (int mt = 0; mt < 4; ++mt)
          acc1[mt][nt1] = __builtin_amdgcn_mfma_f32_16x16x32_f16(am[mt], bfr, acc1[mt][nt1], 0, 0, 0);
      }
    }
#pragma unroll
    for (int nt1 = 0; nt1 < 2; ++nt1) {
      float b1v = b1e[fc * 256 + w * 32 + nt1 * 16 + lr];
#pragma unroll
      for (int mt = 0; mt < 4; ++mt)
#pragma unroll
        for (int r = 0; r < 4; ++r)
          hm[(mt * 16 + lg * 4 + r) * 264 + w * 32 + nt1 * 16 + lr] =
              (_Float16)fmaxf(acc1[mt][nt1][r] + b1v, 0.f);
    }
    __syncthreads();
#pragma unroll
    for (int ks2 = 0; ks2 < 8; ++ks2) {
      half8 am[4];
#pragma unroll
      for (int mt = 0; mt < 4; ++mt)
        am[mt] = *(const half8*)&hm[(mt * 16 + lr) * 264 + ks2 * 32 + lg * 8];
#pragma unroll
      for (int nt = 0; nt < 4; ++nt) {
        half8 bfr = *(const half8*)&w2e[(size_t)(w * 64 + nt * 16 + lr) * NDFF + fc * 256 + ks2 * 32 + lg * 8];
#pragma unroll
        for (int mt = 0; mt < 4; ++mt)
          acc2[mt][nt] = __builtin_amdgcn_mfma_f32_16x16x32_f16(am[mt], bfr, acc2[mt][nt], 0, 0, 0);
      }
    }
    __syncthreads();
  }

  const float* b2e = b2 + e * DMODEL;
#pragma unroll
  for (int nt = 0; nt < 4; ++nt) {
    float b2v = b2e[w * 64 + nt * 16 + lr];
#pragma unroll
    for (int mt = 0; mt < 4; ++mt) {
#pragma unroll
      for (int r = 0; r < 4; ++r) {
        int row = mt * 16 + lg * 4 + r;
        int tk = tk_s[row];
        if (tk >= 0)
          atomicAdd(&Z[(size_t)tk * DMODEL + w * 64 + nt * 16 + lr],
                    (acc2[mt][nt][r] + b2v) * gw_s[row]);
      }
    }
  }
}

// ---------------- launch ----------------
extern "C" void kernel_launch(void* const* d_in, const int* in_sizes, int n_in,
                              void* d_out, int out_size, void* d_ws, size_t ws_size,
                              hipStream_t stream) {
  const float* x     = (const float*)d_in[0];
  const float* emb_w = (const float*)d_in[1];
  const float* wq    = (const float*)d_in[2];
  const float* bq    = (const float*)d_in[3];
  const float* wk    = (const float*)d_in[4];
  const float* bk    = (const float*)d_in[5];
  const float* wv    = (const float*)d_in[6];
  const float* bv    = (const float*)d_in[7];
  const float* wo    = (const float*)d_in[8];
  const float* bo    = (const float*)d_in[9];
  const float* proj  = (const float*)d_in[10];
  const float* ln2g  = (const float*)d_in[11];
  const float* ln2b  = (const float*)d_in[12];
  const float* ln3g  = (const float*)d_in[13];
  const float* ln3b  = (const float*)d_in[14];
  const float* gatew = (const float*)d_in[15];
  const float* gateb = (const float*)d_in[16];
  const float* w1    = (const float*)d_in[17];
  const float* b1    = (const float*)d_in[18];
  const float* w2    = (const float*)d_in[19];
  const float* b2    = (const float*)d_in[20];
  float* out = (float*)d_out;
  float* ws  = (float*)d_ws;

  if (ws_size < F_END * sizeof(float)) {
    fallback_zero_kernel<<<NTOK * 2, 256, 0, stream>>>(out);
    return;
  }

  float* BUF1 = ws + F_BUF1;   // K -> Q -> pre -> Z
  float* BUF2 = out;           // V -> attn -> h1 (d_out reused as scratch)
  int*   cnt  = (int*)(ws + F_CNTI);
  int*   toks = (int*)(ws + F_TOKI);
  float* gwf  = ws + F_GWF;
  _Float16* w1t = (_Float16*)(ws + F_CTX);                  // [E][2048][512] (after attn)
  _Float16* w2t = w1t + (size_t)NEXP * NDFF * DMODEL;       // [E][512][2048]

  zero_cnt_kernel<<<1, 64, 0, stream>>>(cnt);
  proj_pack_kernel<<<80, 256, 0, stream>>>(proj, ws + F_PJT);
  effmat_kernel<<<1536, 128, 0, stream>>>(wq, wk, wv, emb_w, ws + F_EFF);
  // K = x @ Keff^T + bk -> BUF1
  gemm_nt_kernel<<<4096, 256, 0, stream>>>(x, ws + F_EFF + 65536, CIN, nullptr, nullptr, 0, bk, BUF1, DMODEL, 8);
  // V = x @ Veff^T + bv -> BUF2 (d_out)
  gemm_nt_kernel<<<4096, 256, 0, stream>>>(x, ws + F_EFF + 131072, CIN, nullptr, nullptr, 0, bv, BUF2, DMODEL, 8);
  kdash_max_kernel<<<512, 512, 0, stream>>>(BUF1, ws + F_PJT, ws + F_PART);
  reduce_max_kernel<<<1, 256, 0, stream>>>(ws + F_PART, ws + F_STAB, 512);
  ctx_kernel<<<256, 512, 0, stream>>>(BUF1, BUF2, ws + F_PJT, ws + F_STAB, ws + F_CTX, ws + F_KSUM);
  // Q = x @ Qeff^T + bq -> BUF1 (K dead)
  gemm_nt_kernel<<<4096, 256, 0, stream>>>(x, ws + F_EFF, CIN, nullptr, nullptr, 0, bq, BUF1, DMODEL, 8);
  attn_kernel<<<8192, 512, 0, stream>>>(BUF1, ws + F_CTX, ws + F_KSUM, ws + F_PJT, BUF2);
  // ctx now dead: build fp16 transposed weights in its place
  transpose_f16_kernel<<<4096, 256, 0, stream>>>(w1, w1t, DMODEL, NDFF);   // w1t[e][f][k]
  transpose_f16_kernel<<<4096, 256, 0, stream>>>(w2, w2t, NDFF, DMODEL);   // w2t[e][n][f]
  // pre = attn@wo^T + x@emb_w^T + bo -> BUF1
  gemm_nt_kernel<<<4096, 256, 0, stream>>>(BUF2, wo, DMODEL, x, emb_w, CIN, bo, BUF1, DMODEL, 8);
  // h1 = LN(pre) -> BUF2; Z = h1 -> BUF1
  ln_kernel<<<NTOK, 256, 0, stream>>>(BUF1, ln2g, ln2b, BUF2, BUF1);
  gate_kernel<<<8192, 256, 0, stream>>>(BUF2, gatew, gateb, cnt, toks, gwf);
  moe_mfma_kernel<<<4096, 512, 0, stream>>>(BUF2, w1t, b1, w2t, b2, cnt, toks, gwf, BUF1);
  ln_kernel<<<NTOK, 256, 0, stream>>>(BUF1, ln3g, ln3b, out, nullptr);
}

// Round 7
// 4604.765 us; speedup vs baseline: 1.1428x; 1.0082x over previous
//
#include <hip/hip_runtime.h>
#include <math.h>

// Problem dims
#define NBATCH 32
#define NPOS   1024
#define NTOK   32768          // NBATCH*NPOS
#define DMODEL 512
#define NHEAD  8
#define DHD    64
#define MMR    266            // random-feature count
#define NDFF   2048
#define NEXP   4
#define CIN    128            // PL*CIN = flattened patch dim

#define DNSC   0.35355339059327373f   // 64^-0.25
#define RSM    0.06131393394849658f   // 266^-0.5
#define NEG_INF -3.0e38f

typedef _Float16 half8 __attribute__((ext_vector_type(8)));
typedef _Float16 half4 __attribute__((ext_vector_type(4)));
typedef float    f32x4 __attribute__((ext_vector_type(4)));

// ---------------- workspace layout (float offsets) ----------------
static const size_t F_BUF1 = 0;          // 16777216 (K -> Q -> pre -> Z)
static const size_t F_CTX  = 16777216;   // 4358144 (256*266*64); reused for fp16 weights after attn
static const size_t F_KSUM = 21135360;   // 68096 (256*266)
static const size_t F_PART = 21203456;   // 2048
static const size_t F_STAB = 21205504;   // 16
static const size_t F_EFF  = 21205520;   // 3*512*128 = 196608
static const size_t F_CNTI = 21402128;   // 16 (ints)
static const size_t F_TOKI = 21402144;   // 4*32768 ints
static const size_t F_GWF  = 21533216;   // 4*32768 floats
static const size_t F_PJT  = 21664288;   // 20480 floats: packed proj [64][16][20]
static const size_t F_END  = 21684768;

// 17-term register accumulate from the packed proj fragment
#define DASH17(da, q) \
  da[0]+=q*pA.x; da[1]+=q*pA.y; da[2]+=q*pA.z; da[3]+=q*pA.w; \
  da[4]+=q*pB.x; da[5]+=q*pB.y; da[6]+=q*pB.z; da[7]+=q*pB.w; \
  da[8]+=q*pC.x; da[9]+=q*pC.y; da[10]+=q*pC.z; da[11]+=q*pC.w; \
  da[12]+=q*pD.x; da[13]+=q*pD.y; da[14]+=q*pD.z; da[15]+=q*pD.w; \
  da[16]+=q*pE;

// ---------------- fallback (ws too small): write zeros, fail cleanly -----------
__global__ __launch_bounds__(256) void fallback_zero_kernel(float* __restrict__ out) {
  out[(size_t)blockIdx.x * 256 + threadIdx.x] = 0.f;
}

// ---------------- pack proj: projT[d*320 + g*20 + j] = proj[(g*17+j)*64 + d] ----------
__global__ __launch_bounds__(256) void proj_pack_kernel(
    const float* __restrict__ proj, float* __restrict__ projT)
{
  int idx = blockIdx.x * 256 + threadIdx.x;
  if (idx >= 20480) return;
  int d = idx / 320, rem = idx % 320;
  int g = rem / 20, j = rem % 20;
  int m = g * 17 + j;
  projT[idx] = (j < 17 && m < MMR) ? proj[m * 64 + d] : 0.f;
}

// ---------------- effective QKV matrices: eff[mat] = W[mat] @ emb_w  (512x128) ----------
__global__ __launch_bounds__(128) void effmat_kernel(
    const float* __restrict__ wq, const float* __restrict__ wk, const float* __restrict__ wv,
    const float* __restrict__ emb, float* __restrict__ eff)
{
  __shared__ float wrow[512];
  const int bid = blockIdx.x;          // 0..1535
  const int mat = bid >> 9;
  const int n   = bid & 511;
  const float* W = (mat == 0) ? wq : ((mat == 1) ? wk : wv);
  const int tid = threadIdx.x;         // 128
  for (int i = tid; i < 512; i += 128) wrow[i] = W[n * 512 + i];
  __syncthreads();
  float acc = 0.f;
  for (int d = 0; d < 512; ++d) acc += wrow[d] * emb[d * CIN + tid];
  eff[mat * 65536 + n * CIN + tid] = acc;
}

// ------- generic GEMM: C = A(MxK)*W(NxK)^T [+ A2(MxK2)*W2(NxK2)^T] + bias --------------
__global__ __launch_bounds__(256) void gemm_nt_kernel(
    const float* __restrict__ A, const float* __restrict__ W, int K,
    const float* __restrict__ A2, const float* __restrict__ W2, int K2,
    const float* __restrict__ bias, float* __restrict__ C, int N, int ncb)
{
  __shared__ float As[32][64];
  __shared__ float Ws[32][64];
  const int tid  = threadIdx.x;
  const int bx   = blockIdx.x % ncb;
  const int by   = blockIdx.x / ncb;
  const int row0 = by * 64, col0 = bx * 64;
  const int tx   = tid & 15, ty = tid >> 4;
  const int lr   = tid >> 3;
  const int lk   = (tid & 7) * 4;
  float acc[4][4] = {};
  for (int pass = 0; pass < 2; ++pass) {
    const float* Ap = pass ? A2 : A;
    const float* Wp = pass ? W2 : W;
    const int    Kp = pass ? K2 : K;
    if (!Ap) continue;
    for (int k0 = 0; k0 < Kp; k0 += 32) {
      __syncthreads();
#pragma unroll
      for (int rr = 0; rr < 2; ++rr) {
        const int r = lr + rr * 32;
        float4 a4 = *(const float4*)&Ap[(size_t)(row0 + r) * Kp + k0 + lk];
        As[lk + 0][r] = a4.x; As[lk + 1][r] = a4.y; As[lk + 2][r] = a4.z; As[lk + 3][r] = a4.w;
        float4 w4 = *(const float4*)&Wp[(size_t)(col0 + r) * Kp + k0 + lk];
        Ws[lk + 0][r] = w4.x; Ws[lk + 1][r] = w4.y; Ws[lk + 2][r] = w4.z; Ws[lk + 3][r] = w4.w;
      }
      __syncthreads();
#pragma unroll
      for (int kk = 0; kk < 32; ++kk) {
        float4 av = *(const float4*)&As[kk][ty * 4];
        float4 wv = *(const float4*)&Ws[kk][tx * 4];
        acc[0][0] += av.x * wv.x; acc[0][1] += av.x * wv.y; acc[0][2] += av.x * wv.z; acc[0][3] += av.x * wv.w;
        acc[1][0] += av.y * wv.x; acc[1][1] += av.y * wv.y; acc[1][2] += av.y * wv.z; acc[1][3] += av.y * wv.w;
        acc[2][0] += av.z * wv.x; acc[2][1] += av.z * wv.y; acc[2][2] += av.z * wv.z; acc[2][3] += av.z * wv.w;
        acc[3][0] += av.w * wv.x; acc[3][1] += av.w * wv.y; acc[3][2] += av.w * wv.z; acc[3][3] += av.w * wv.w;
      }
    }
  }
#pragma unroll
  for (int i = 0; i < 4; ++i) {
    const int row = row0 + ty * 4 + i;
    const int col = col0 + tx * 4;
    float4 o = make_float4(acc[i][0], acc[i][1], acc[i][2], acc[i][3]);
    if (bias) {
      float4 b4 = *(const float4*)&bias[col];
      o.x += b4.x; o.y += b4.y; o.z += b4.z; o.w += b4.w;
    }
    *(float4*)&C[(size_t)row * N + col] = o;
  }
}

// ---------------- global max of k-dash: 512 thr, 512 rows/block, 16-row chunks ----------
__global__ __launch_bounds__(512, 1) void kdash_max_kernel(
    const float* __restrict__ Kbuf, const float* __restrict__ projT, float* __restrict__ partial)
{
  __shared__ float pjG[20480];
  __shared__ float kl[16 * 68];
  __shared__ float red[512];
  const int tid = threadIdx.x;
  for (int i4 = tid; i4 < 5120; i4 += 512)
    ((float4*)pjG)[i4] = ((const float4*)projT)[i4];
  const int w = tid >> 6, l = tid & 63;
  const int ml = l & 15, ds = l >> 4;
  const int dbase = ds * 16;
  const int r0 = 2 * w;
  float mxl = NEG_INF;
  for (int t = 0; t < 32; ++t) {
    __syncthreads();
    for (int idx = tid; idx < 1024; idx += 512) {
      int r = idx >> 6, dd = idx & 63;
      kl[r * 68 + dd] = Kbuf[((size_t)blockIdx.x * 512 + t * 16 + r) * 64 + dd] * DNSC;
    }
    __syncthreads();
    float da0[17], da1[17];
#pragma unroll
    for (int j = 0; j < 17; ++j) { da0[j] = 0.f; da1[j] = 0.f; }
    for (int dd = 0; dd < 16; ++dd) {
      int d = dbase + dd;
      float q0 = kl[r0 * 68 + d], q1 = kl[r0 * 68 + 68 + d];
      const float* pr = &pjG[d * 320 + ml * 20];
      float4 pA = *(const float4*)pr, pB = *(const float4*)(pr + 4),
             pC = *(const float4*)(pr + 8), pD = *(const float4*)(pr + 12);
      float pE = pr[16];
      DASH17(da0, q0)
      DASH17(da1, q1)
    }
#pragma unroll
    for (int j = 0; j < 17; ++j) {
      da0[j] += __shfl_xor(da0[j], 16); da0[j] += __shfl_xor(da0[j], 32);
      da1[j] += __shfl_xor(da1[j], 16); da1[j] += __shfl_xor(da1[j], 32);
    }
#pragma unroll
    for (int j = 0; j < 17; ++j) {
      int m = ml * 17 + j;
      if (m < MMR) { mxl = fmaxf(mxl, da0[j]); mxl = fmaxf(mxl, da1[j]); }
    }
  }
  red[tid] = mxl;
  __syncthreads();
  for (int st = 256; st > 0; st >>= 1) {
    if (tid < st) red[tid] = fmaxf(red[tid], red[tid + st]);
    __syncthreads();
  }
  if (tid == 0) partial[blockIdx.x] = red[0];
}

__global__ __launch_bounds__(256) void reduce_max_kernel(
    const float* __restrict__ part, float* __restrict__ stab, int n)
{
  __shared__ float red[256];
  float m = NEG_INF;
  for (int i = threadIdx.x; i < n; i += 256) m = fmaxf(m, part[i]);
  red[threadIdx.x] = m;
  __syncthreads();
  for (int st = 128; st > 0; st >>= 1) {
    if (threadIdx.x < st) red[threadIdx.x] = fmaxf(red[threadIdx.x], red[threadIdx.x + st]);
    __syncthreads();
  }
  if (threadIdx.x == 0) stab[0] = red[0];
}

// ---------------- ctx = kp^T @ v, ksum = sum kp; one (b,h)/block, 512 thr ----------
__global__ __launch_bounds__(512, 1) void ctx_kernel(
    const float* __restrict__ Kbuf, const float* __restrict__ Vbuf,
    const float* __restrict__ projT, const float* __restrict__ stabp,
    float* __restrict__ ctxg, float* __restrict__ ksumg)
{
  __shared__ float pjG[20480];
  __shared__ float kl[16 * 68];
  __shared__ float vl[16 * 68];
  __shared__ _Float16 kp16[16 * 640];   // 16 rows x (16 groups x 40-pad halfs)
  __shared__ float ks[272];
  const int tid = threadIdx.x;
  const int bh = blockIdx.x;
  const int b = bh >> 3, h = bh & 7;
  const float stab = stabp[0];
  for (int i4 = tid; i4 < 5120; i4 += 512)
    ((float4*)pjG)[i4] = ((const float4*)projT)[i4];
  if (tid < 272) ks[tid] = 0.f;
  const int w = tid >> 6, l = tid & 63;
  const int ml = l & 15, ds = l >> 4;
  const int dbase = ds * 16;
  const int r0 = 2 * w;
  const int jh = ds >> 1, rsel = ds & 1;
  const int d = l;
  // ksum mapping for tid<272: m=tid -> group g, in-group j
  const int ksg = tid / 17, ksj = tid - ksg * 17;
  float acc[2][17];
#pragma unroll
  for (int g = 0; g < 2; ++g)
#pragma unroll
    for (int j = 0; j < 17; ++j) acc[g][j] = 0.f;

  for (int t = 0; t < 64; ++t) {
    __syncthreads();
    for (int idx = tid; idx < 1024; idx += 512) {
      int r = idx >> 6, dd = idx & 63;
      size_t gg = ((size_t)(b * NPOS + t * 16 + r)) * DMODEL + h * DHD + dd;
      kl[r * 68 + dd] = Kbuf[gg] * DNSC;
      vl[r * 68 + dd] = Vbuf[gg];
    }
    __syncthreads();
    // dash for rows r0, r0+1 (partial over d-quarter, reduce over ds)
    float da0[17], da1[17]; float dg0 = 0.f, dg1 = 0.f;
#pragma unroll
    for (int j = 0; j < 17; ++j) { da0[j] = 0.f; da1[j] = 0.f; }
    for (int dd = 0; dd < 16; ++dd) {
      int dq = dbase + dd;
      float q0 = kl[r0 * 68 + dq], q1 = kl[r0 * 68 + 68 + dq];
      const float* pr = &pjG[dq * 320 + ml * 20];
      float4 pA = *(const float4*)pr, pB = *(const float4*)(pr + 4),
             pC = *(const float4*)(pr + 8), pD = *(const float4*)(pr + 12);
      float pE = pr[16];
      dg0 += q0 * q0; dg1 += q1 * q1;
      DASH17(da0, q0)
      DASH17(da1, q1)
    }
#pragma unroll
    for (int j = 0; j < 17; ++j) {
      da0[j] += __shfl_xor(da0[j], 16); da0[j] += __shfl_xor(da0[j], 32);
      da1[j] += __shfl_xor(da1[j], 16); da1[j] += __shfl_xor(da1[j], 32);
    }
    dg0 += __shfl_xor(dg0, 16); dg0 += __shfl_xor(dg0, 32);
    dg1 += __shfl_xor(dg1, 16); dg1 += __shfl_xor(dg1, 32);
    // exp: lane handles row r0+rsel, strided j = 2k+jh
    float dgx = rsel ? dg1 : dg0;
    const int irow = r0 + rsel;
#pragma unroll
    for (int k = 0; k < 9; ++k) {
      int j = 2 * k + jh;
      if (j < 17) {
        int m = ml * 17 + j;
        float dv = rsel ? da1[j] : da0[j];
        float v = 0.f;
        if (m < MMR) v = RSM * (expf(dv - 0.5f * dgx - stab) + 1e-4f);
        kp16[irow * 640 + ml * 40 + j] = (_Float16)v;
      }
    }
    __syncthreads();
    // ksum accumulation: thread tid<272 owns m=tid
    if (tid < 272) {
      float s = 0.f;
      const _Float16* kb = &kp16[ksg * 40 + ksj];
#pragma unroll
      for (int i = 0; i < 16; ++i) s += (float)kb[i * 640];
      ks[tid] += s;
    }
    // PV: wave owns m-groups {2w, 2w+1}; lane owns output dim d
    for (int i = 0; i < 16; ++i) {
      float vv = vl[i * 68 + d];
#pragma unroll
      for (int g = 0; g < 2; ++g) {
        const _Float16* kr = &kp16[i * 640 + (2 * w + g) * 40];
        half8 kA = *(const half8*)kr;
        half8 kB = *(const half8*)(kr + 8);
        float kE = (float)kr[16];
        acc[g][0] += (float)kA[0] * vv; acc[g][1] += (float)kA[1] * vv;
        acc[g][2] += (float)kA[2] * vv; acc[g][3] += (float)kA[3] * vv;
        acc[g][4] += (float)kA[4] * vv; acc[g][5] += (float)kA[5] * vv;
        acc[g][6] += (float)kA[6] * vv; acc[g][7] += (float)kA[7] * vv;
        acc[g][8] += (float)kB[0] * vv; acc[g][9] += (float)kB[1] * vv;
        acc[g][10] += (float)kB[2] * vv; acc[g][11] += (float)kB[3] * vv;
        acc[g][12] += (float)kB[4] * vv; acc[g][13] += (float)kB[5] * vv;
        acc[g][14] += (float)kB[6] * vv; acc[g][15] += (float)kB[7] * vv;
        acc[g][16] += kE * vv;
      }
    }
  }
  const size_t cb = (size_t)bh * MMR * DHD;
#pragma unroll
  for (int g = 0; g < 2; ++g)
#pragma unroll
    for (int j = 0; j < 17; ++j) {
      int m = (2 * w + g) * 17 + j;
      if (m < MMR) ctxg[cb + (size_t)m * 64 + d] = acc[g][j];
    }
  if (tid < MMR) ksumg[bh * MMR + tid] = ks[tid];
}

// ---------------- attn = (qp @ ctx)/den; 512 thr, 32 rows/block ----------------
__global__ __launch_bounds__(512, 1) void attn_kernel(
    const float* __restrict__ Qbuf, const float* __restrict__ ctxg,
    const float* __restrict__ ksumg, const float* __restrict__ projT,
    float* __restrict__ attnb)
{
  __shared__ float pjG[20480];
  __shared__ float ql[32 * 68];
  __shared__ _Float16 qp16[32 * 640];
  __shared__ float ks[272];
  __shared__ float den_s[32];
  const int tid = threadIdx.x;
  const int bh = blockIdx.x >> 5;
  const int n0 = (blockIdx.x & 31) * 32;
  const int b = bh >> 3, h = bh & 7;
  for (int i4 = tid; i4 < 5120; i4 += 512)
    ((float4*)pjG)[i4] = ((const float4*)projT)[i4];
  if (tid < 272) ks[tid] = (tid < MMR) ? ksumg[bh * MMR + tid] : 0.f;
  for (int idx = tid; idx < 2048; idx += 512) {
    int r = idx >> 6, dd = idx & 63;
    ql[r * 68 + dd] = Qbuf[((size_t)(b * NPOS + n0 + r)) * DMODEL + h * DHD + dd] * DNSC;
  }
  __syncthreads();
  const int w = tid >> 6, l = tid & 63;
  const int ml = l & 15, ds = l >> 4;
  const int dbase = ds * 16;
  const int jh = ds >> 1, rsel = ds & 1;
  for (int s = 0; s < 2; ++s) {
    const int r0 = s * 16 + 2 * w;
    float da0[17], da1[17]; float dg0 = 0.f, dg1 = 0.f;
#pragma unroll
    for (int j = 0; j < 17; ++j) { da0[j] = 0.f; da1[j] = 0.f; }
    for (int dd = 0; dd < 16; ++dd) {
      int dq = dbase + dd;
      float q0 = ql[r0 * 68 + dq], q1 = ql[r0 * 68 + 68 + dq];
      const float* pr = &pjG[dq * 320 + ml * 20];
      float4 pA = *(const float4*)pr, pB = *(const float4*)(pr + 4),
             pC = *(const float4*)(pr + 8), pD = *(const float4*)(pr + 12);
      float pE = pr[16];
      dg0 += q0 * q0; dg1 += q1 * q1;
      DASH17(da0, q0)
      DASH17(da1, q1)
    }
#pragma unroll
    for (int j = 0; j < 17; ++j) {
      da0[j] += __shfl_xor(da0[j], 16); da0[j] += __shfl_xor(da0[j], 32);
      da1[j] += __shfl_xor(da1[j], 16); da1[j] += __shfl_xor(da1[j], 32);
    }
    dg0 += __shfl_xor(dg0, 16); dg0 += __shfl_xor(dg0, 32);
    dg1 += __shfl_xor(dg1, 16); dg1 += __shfl_xor(dg1, 32);
    // per-row max over valid m (reduce over ml lanes)
    float mx0 = NEG_INF, mx1 = NEG_INF;
#pragma unroll
    for (int j = 0; j < 17; ++j) {
      int m = ml * 17 + j;
      if (m < MMR) { mx0 = fmaxf(mx0, da0[j]); mx1 = fmaxf(mx1, da1[j]); }
    }
#pragma unroll
    for (int off = 1; off < 16; off <<= 1) {
      mx0 = fmaxf(mx0, __shfl_xor(mx0, off));
      mx1 = fmaxf(mx1, __shfl_xor(mx1, off));
    }
    float dgx = rsel ? dg1 : dg0;
    float mxx = rsel ? mx1 : mx0;
    const int row = r0 + rsel;
    float dp = 0.f;
#pragma unroll
    for (int k = 0; k < 9; ++k) {
      int j = 2 * k + jh;
      if (j < 17) {
        int m = ml * 17 + j;
        float dv = rsel ? da1[j] : da0[j];
        float v = 0.f;
        if (m < MMR) { v = RSM * (expf(dv - 0.5f * dgx - mxx) + 1e-4f); dp += v * ks[m]; }
        qp16[row * 640 + ml * 40 + j] = (_Float16)v;
      }
    }
    dp += __shfl_xor(dp, 1); dp += __shfl_xor(dp, 2); dp += __shfl_xor(dp, 4);
    dp += __shfl_xor(dp, 8); dp += __shfl_xor(dp, 32);
    if ((l & 47) == 0) den_s[row] = dp;   // lanes 0 (rsel=0) and 16 (rsel=1)
  }
  __syncthreads();
  // PV: wave wg owns 4 rows, lane = output d
  const int wg = tid >> 6, lane = tid & 63;
  float acc[4] = {0.f, 0.f, 0.f, 0.f};
  const float* cb = ctxg + (size_t)bh * MMR * DHD + lane;
  for (int g = 0; g < 16; ++g) {
    float cv[17];
#pragma unroll
    for (int j = 0; j < 17; ++j) cv[j] = cb[(size_t)(g * 17 + j) * 64];
#pragma unroll
    for (int tt = 0; tt < 4; ++tt) {
      const _Float16* qr = &qp16[(wg * 4 + tt) * 640 + g * 40];
      half8 qA = *(const half8*)qr;
      half8 qB = *(const half8*)(qr + 8);
      float qE = (float)qr[16];
      acc[tt] += (float)qA[0] * cv[0] + (float)qA[1] * cv[1] + (float)qA[2] * cv[2]
               + (float)qA[3] * cv[3] + (float)qA[4] * cv[4] + (float)qA[5] * cv[5]
               + (float)qA[6] * cv[6] + (float)qA[7] * cv[7]
               + (float)qB[0] * cv[8] + (float)qB[1] * cv[9] + (float)qB[2] * cv[10]
               + (float)qB[3] * cv[11] + (float)qB[4] * cv[12] + (float)qB[5] * cv[13]
               + (float)qB[6] * cv[14] + (float)qB[7] * cv[15]
               + qE * cv[16];
    }
  }
#pragma unroll
  for (int tt = 0; tt < 4; ++tt) {
    int r = wg * 4 + tt;
    attnb[((size_t)(b * NPOS + n0 + r)) * DMODEL + h * DHD + lane] = acc[tt] / den_s[r];
  }
}

// ---------------- LayerNorm (one block per row); optional second output ----------------
__global__ __launch_bounds__(256) void ln_kernel(
    const float* __restrict__ in, const float* __restrict__ g, const float* __restrict__ bb,
    float* __restrict__ out, float* __restrict__ out2)
{
  const int row = blockIdx.x, tid = threadIdx.x;
  float2 x = *(const float2*)&in[(size_t)row * DMODEL + tid * 2];
  float s = x.x + x.y, sq = x.x * x.x + x.y * x.y;
#pragma unroll
  for (int off = 32; off > 0; off >>= 1) {
    s += __shfl_down(s, off);
    sq += __shfl_down(sq, off);
  }
  __shared__ float ps[4], pq[4];
  __shared__ float smu, srv;
  const int wv = tid >> 6, ln = tid & 63;
  if (ln == 0) { ps[wv] = s; pq[wv] = sq; }
  __syncthreads();
  if (tid == 0) {
    float S = ps[0] + ps[1] + ps[2] + ps[3];
    float Q = pq[0] + pq[1] + pq[2] + pq[3];
    float mu = S / 512.f;
    float var = Q / 512.f - mu * mu;
    smu = mu;
    srv = 1.0f / sqrtf(var + 1e-5f);
  }
  __syncthreads();
  const float mu = smu, rv = srv;
  const int c = tid * 2;
  float y0 = (x.x - mu) * rv * g[c] + bb[c];
  float y1 = (x.y - mu) * rv * g[c + 1] + bb[c + 1];
  out[(size_t)row * DMODEL + c] = y0;
  out[(size_t)row * DMODEL + c + 1] = y1;
  if (out2) {
    out2[(size_t)row * DMODEL + c] = y0;
    out2[(size_t)row * DMODEL + c + 1] = y1;
  }
}

// ---------------- gating ----------------
__global__ __launch_bounds__(64) void zero_cnt_kernel(int* __restrict__ cnt)
{
  if (threadIdx.x < NEXP) cnt[threadIdx.x] = 0;
}

__global__ __launch_bounds__(256) void gate_kernel(
    const float* __restrict__ h1, const float* __restrict__ gw, const float* __restrict__ gb,
    int* __restrict__ cnt, int* __restrict__ toks, float* __restrict__ gws)
{
  const int wv = threadIdx.x >> 6, ln = threadIdx.x & 63;
  const int tok = blockIdx.x * 4 + wv;
  const float* hr = h1 + (size_t)tok * DMODEL;
  float p0 = 0, p1 = 0, p2 = 0, p3 = 0;
#pragma unroll
  for (int k = 0; k < 8; ++k) {
    float xv = hr[ln + 64 * k];
    p0 += xv * gw[0 * DMODEL + ln + 64 * k];
    p1 += xv * gw[1 * DMODEL + ln + 64 * k];
    p2 += xv * gw[2 * DMODEL + ln + 64 * k];
    p3 += xv * gw[3 * DMODEL + ln + 64 * k];
  }
#pragma unroll
  for (int off = 32; off > 0; off >>= 1) {
    p0 += __shfl_down(p0, off);
    p1 += __shfl_down(p1, off);
    p2 += __shfl_down(p2, off);
    p3 += __shfl_down(p3, off);
  }
  if (ln == 0) {
    p0 += gb[0]; p1 += gb[1]; p2 += gb[2]; p3 += gb[3];
    int i0 = 0; float v0 = p0;
    if (p1 > v0) { v0 = p1; i0 = 1; }
    if (p2 > v0) { v0 = p2; i0 = 2; }
    if (p3 > v0) { v0 = p3; i0 = 3; }
    int i1 = -1; float v1 = NEG_INF;
    if (i0 != 0 && p0 > v1) { v1 = p0; i1 = 0; }
    if (i0 != 1 && p1 > v1) { v1 = p1; i1 = 1; }
    if (i0 != 2 && p2 > v1) { v1 = p2; i1 = 2; }
    if (i0 != 3 && p3 > v1) { v1 = p3; i1 = 3; }
    float e = expf(v1 - v0);
    float w0 = 1.f / (1.f + e);
    float w1 = e / (1.f + e);
    int pos0 = atomicAdd(&cnt[i0], 1);
    toks[i0 * NTOK + pos0] = tok;
    gws[i0 * NTOK + pos0] = w0;
    int pos1 = atomicAdd(&cnt[i1], 1);
    toks[i1 * NTOK + pos1] = tok;
    gws[i1 * NTOK + pos1] = w1;
  }
}

// ---------------- weight transpose + fp32->fp16 ----------------
__global__ __launch_bounds__(256) void transpose_f16_kernel(
    const float* __restrict__ in, _Float16* __restrict__ outp, int R, int C)
{
  __shared__ float tl[32][33];
  const int bid = blockIdx.x;
  const int e  = bid >> 10;
  const int t2 = bid & 1023;
  const int tC = C >> 5;
  const int r0 = (t2 / tC) << 5;
  const int c0 = (t2 % tC) << 5;
  const float* ine  = in   + (size_t)e * R * C;
  _Float16*    oute = outp + (size_t)e * R * C;
  const int ci = threadIdx.x & 31, ri = threadIdx.x >> 5;
#pragma unroll
  for (int i = 0; i < 4; ++i)
    tl[ri + i * 8][ci] = ine[(size_t)(r0 + ri + i * 8) * C + c0 + ci];
  __syncthreads();
  const int rr = threadIdx.x & 31, cc = threadIdx.x >> 5;
#pragma unroll
  for (int i = 0; i < 4; ++i)
    oute[(size_t)(c0 + cc + i * 8) * R + r0 + rr] = (_Float16)tl[rr][cc + i * 8];
}

// ---------------- grouped MoE via fp16 MFMA, square-blocked ----------------------------
__global__ __launch_bounds__(512) void moe_mfma_kernel(
    const float* __restrict__ h1, const _Float16* __restrict__ w1t, const float* __restrict__ b1,
    const _Float16* __restrict__ w2t, const float* __restrict__ b2,
    const int* __restrict__ cnt, const int* __restrict__ toks, const float* __restrict__ gws,
    float* __restrict__ Z)
{
  __shared__ _Float16 t_lds[64 * 520];
  __shared__ _Float16 hm[64 * 264];
  __shared__ int   tk_s[64];
  __shared__ float gw_s[64];
  const int tid = threadIdx.x;
  const int e = blockIdx.x >> 10;
  const int tile = blockIdx.x & 1023;
  const int cn = cnt[e];
  if (tile * 64 >= cn) return;
  if (tid < 64) {
    int idx = tile * 64 + tid;
    if (idx < cn) { tk_s[tid] = toks[e * NTOK + idx]; gw_s[tid] = gws[e * NTOK + idx]; }
    else          { tk_s[tid] = -1;                   gw_s[tid] = 0.f; }
  }
  __syncthreads();
  for (int it = tid; it < 64 * 128; it += 512) {
    int r = it >> 7, c4 = (it & 127) * 4;
    int tk = tk_s[r];
    float4 v = make_float4(0.f, 0.f, 0.f, 0.f);
    if (tk >= 0) v = *(const float4*)&h1[(size_t)tk * DMODEL + c4];
    _Float16* p = &t_lds[r * 520 + c4];
    p[0] = (_Float16)v.x; p[1] = (_Float16)v.y; p[2] = (_Float16)v.z; p[3] = (_Float16)v.w;
  }
  __syncthreads();

  const int w = tid >> 6, l = tid & 63;
  const int lr = l & 15, lg = l >> 4;
  const _Float16* w1e = w1t + (size_t)e * NDFF * DMODEL;
  const _Float16* w2e = w2t + (size_t)e * DMODEL * NDFF;
  const float* b1e = b1 + e * NDFF;

  f32x4 acc2[4][4];
#pragma unroll
  for (int mt = 0; mt < 4; ++mt)
#pragma unroll
    for (int nt = 0; nt < 4; ++nt) acc2[mt][nt] = (f32x4){0.f, 0.f, 0.f, 0.f};

  for (int fc = 0; fc < 8; ++fc) {
    f32x4 acc1[4][2];
#pragma unroll
    for (int mt = 0; mt < 4; ++mt)
#pragma unroll
      for (int nt1 = 0; nt1 < 2; ++nt1) acc1[mt][nt1] = (f32x4){0.f, 0.f, 0.f, 0.f};
#pragma unroll
    for (int ks = 0; ks < 16; ++ks) {
      half8 am[4];
#pragma unroll
      for (int mt = 0; mt < 4; ++mt)
        am[mt] = *(const half8*)&t_lds[(mt * 16 + lr) * 520 + ks * 32 + lg * 8];
#pragma unroll
      for (int nt1 = 0; nt1 < 2; ++nt1) {
        half8 bfr = *(const half8*)&w1e[(size_t)(fc * 256 + w * 32 + nt1 * 16 + lr) * DMODEL + ks * 32 + lg * 8];
#pragma unroll
        for (int mt = 0; mt < 4; ++mt)
          acc1[mt][nt1] = __builtin_amdgcn_mfma_f32_16x16x32_f16(am[mt], bfr, acc1[mt][nt1], 0, 0, 0);
      }
    }
#pragma unroll
    for (int nt1 = 0; nt1 < 2; ++nt1) {
      float b1v = b1e[fc * 256 + w * 32 + nt1 * 16 + lr];
#pragma unroll
      for (int mt = 0; mt < 4; ++mt)
#pragma unroll
        for (int r = 0; r < 4; ++r)
          hm[(mt * 16 + lg * 4 + r) * 264 + w * 32 + nt1 * 16 + lr] =
              (_Float16)fmaxf(acc1[mt][nt1][r] + b1v, 0.f);
    }
    __syncthreads();
#pragma unroll
    for (int ks2 = 0; ks2 < 8; ++ks2) {
      half8 am[4];
#pragma unroll
      for (int mt = 0; mt < 4; ++mt)
        am[mt] = *(const half8*)&hm[(mt * 16 + lr) * 264 + ks2 * 32 + lg * 8];
#pragma unroll
      for (int nt = 0; nt < 4; ++nt) {
        half8 bfr = *(const half8*)&w2e[(size_t)(w * 64 + nt * 16 + lr) * NDFF + fc * 256 + ks2 * 32 + lg * 8];
#pragma unroll
        for (int mt = 0; mt < 4; ++mt)
          acc2[mt][nt] = __builtin_amdgcn_mfma_f32_16x16x32_f16(am[mt], bfr, acc2[mt][nt], 0, 0, 0);
      }
    }
    __syncthreads();
  }

  const float* b2e = b2 + e * DMODEL;
#pragma unroll
  for (int nt = 0; nt < 4; ++nt) {
    float b2v = b2e[w * 64 + nt * 16 + lr];
#pragma unroll
    for (int mt = 0; mt < 4; ++mt) {
#pragma unroll
      for (int r = 0; r < 4; ++r) {
        int row = mt * 16 + lg * 4 + r;
        int tk = tk_s[row];
        if (tk >= 0)
          atomicAdd(&Z[(size_t)tk * DMODEL + w * 64 + nt * 16 + lr],
                    (acc2[mt][nt][r] + b2v) * gw_s[row]);
      }
    }
  }
}

// ---------------- launch ----------------
extern "C" void kernel_launch(void* const* d_in, const int* in_sizes, int n_in,
                              void* d_out, int out_size, void* d_ws, size_t ws_size,
                              hipStream_t stream) {
  const float* x     = (const float*)d_in[0];
  const float* emb_w = (const float*)d_in[1];
  const float* wq    = (const float*)d_in[2];
  const float* bq    = (const float*)d_in[3];
  const float* wk    = (const float*)d_in[4];
  const float* bk    = (const float*)d_in[5];
  const float* wv    = (const float*)d_in[6];
  const float* bv    = (const float*)d_in[7];
  const float* wo    = (const float*)d_in[8];
  const float* bo    = (const float*)d_in[9];
  const float* proj  = (const float*)d_in[10];
  const float* ln2g  = (const float*)d_in[11];
  const float* ln2b  = (const float*)d_in[12];
  const float* ln3g  = (const float*)d_in[13];
  const float* ln3b  = (const float*)d_in[14];
  const float* gatew = (const float*)d_in[15];
  const float* gateb = (const float*)d_in[16];
  const float* w1    = (const float*)d_in[17];
  const float* b1    = (const float*)d_in[18];
  const float* w2    = (const float*)d_in[19];
  const float* b2    = (const float*)d_in[20];
  float* out = (float*)d_out;
  float* ws  = (float*)d_ws;

  if (ws_size < F_END * sizeof(float)) {
    fallback_zero_kernel<<<NTOK * 2, 256, 0, stream>>>(out);
    return;
  }

  float* BUF1 = ws + F_BUF1;   // K -> Q -> pre -> Z
  float* BUF2 = out;           // V -> attn -> h1 (d_out reused as scratch)
  int*   cnt  = (int*)(ws + F_CNTI);
  int*   toks = (int*)(ws + F_TOKI);
  float* gwf  = ws + F_GWF;
  _Float16* w1t = (_Float16*)(ws + F_CTX);                  // [E][2048][512] (after attn)
  _Float16* w2t = w1t + (size_t)NEXP * NDFF * DMODEL;       // [E][512][2048]

  zero_cnt_kernel<<<1, 64, 0, stream>>>(cnt);
  proj_pack_kernel<<<80, 256, 0, stream>>>(proj, ws + F_PJT);
  effmat_kernel<<<1536, 128, 0, stream>>>(wq, wk, wv, emb_w, ws + F_EFF);
  // K = x @ Keff^T + bk -> BUF1
  gemm_nt_kernel<<<4096, 256, 0, stream>>>(x, ws + F_EFF + 65536, CIN, nullptr, nullptr, 0, bk, BUF1, DMODEL, 8);
  // V = x @ Veff^T + bv -> BUF2 (d_out)
  gemm_nt_kernel<<<4096, 256, 0, stream>>>(x, ws + F_EFF + 131072, CIN, nullptr, nullptr, 0, bv, BUF2, DMODEL, 8);
  kdash_max_kernel<<<512, 512, 0, stream>>>(BUF1, ws + F_PJT, ws + F_PART);
  reduce_max_kernel<<<1, 256, 0, stream>>>(ws + F_PART, ws + F_STAB, 512);
  ctx_kernel<<<256, 512, 0, stream>>>(BUF1, BUF2, ws + F_PJT, ws + F_STAB, ws + F_CTX, ws + F_KSUM);
  // Q = x @ Qeff^T + bq -> BUF1 (K dead)
  gemm_nt_kernel<<<4096, 256, 0, stream>>>(x, ws + F_EFF, CIN, nullptr, nullptr, 0, bq, BUF1, DMODEL, 8);
  attn_kernel<<<8192, 512, 0, stream>>>(BUF1, ws + F_CTX, ws + F_KSUM, ws + F_PJT, BUF2);
  // ctx now dead: build fp16 transposed weights in its place
  transpose_f16_kernel<<<4096, 256, 0, stream>>>(w1, w1t, DMODEL, NDFF);   // w1t[e][f][k]
  transpose_f16_kernel<<<4096, 256, 0, stream>>>(w2, w2t, NDFF, DMODEL);   // w2t[e][n][f]
  // pre = attn@wo^T + x@emb_w^T + bo -> BUF1
  gemm_nt_kernel<<<4096, 256, 0, stream>>>(BUF2, wo, DMODEL, x, emb_w, CIN, bo, BUF1, DMODEL, 8);
  // h1 = LN(pre) -> BUF2; Z = h1 -> BUF1
  ln_kernel<<<NTOK, 256, 0, stream>>>(BUF1, ln2g, ln2b, BUF2, BUF1);
  gate_kernel<<<8192, 256, 0, stream>>>(BUF2, gatew, gateb, cnt, toks, gwf);
  moe_mfma_kernel<<<4096, 512, 0, stream>>>(BUF2, w1t, b1, w2t, b2, cnt, toks, gwf, BUF1);
  ln_kernel<<<NTOK, 256, 0, stream>>>(BUF1, ln3g, ln3b, out, nullptr);
}